// Round 1
// baseline (202.100 us; speedup 1.0000x reference)
//
#include <hip/hip_runtime.h>
#include <hip/hip_bf16.h>

typedef __bf16 bf16_t;
typedef __bf16 bf16x8 __attribute__((ext_vector_type(8)));
typedef float f32x4 __attribute__((ext_vector_type(4)));

#define S_TOT 12288
#define F_IN 128
#define F_OUT 256
#define EPS 1e-5f

static __device__ __forceinline__ float silu_f(float v) {
  return v / (1.0f + __expf(-v));
}

// ---------------- pack weights into MFMA B-frag order ----------------
// Unit = (k, kc, cb): 16x32 B-subtile; lane l holds B[f=32kc+8*(l>>4)+j][o=16cb+(l&15)]
// stored at unit*1024B + l*16B. W1: 9*4*16=576 units; W2: 9*8*16=1152; Wsk: 4*16=64.
__global__ void pack_weights(const float* __restrict__ W1,
                             const float* __restrict__ W2,
                             const float* __restrict__ Wsk,
                             bf16_t* __restrict__ W1p,
                             bf16_t* __restrict__ W2p,
                             bf16_t* __restrict__ Wsp) {
  int w = blockIdx.x * 4 + (threadIdx.x >> 6);
  int l = threadIdx.x & 63;
  int lo = l & 15, hi = l >> 4;
  const float* src;
  bf16_t* dst;
  int fbase, obase;
  if (w < 576) {
    int k = w >> 6, rem = w & 63, kc = rem >> 4, cb = rem & 15;
    src = W1 + k * 32768;
    dst = W1p + (size_t)w * 512;
    fbase = 32 * kc + 8 * hi; obase = 16 * cb + lo;
  } else if (w < 1728) {
    int idx = w - 576;
    int k = idx >> 7, rem = idx & 127, kc = rem >> 4, cb = rem & 15;
    src = W2 + k * 65536;
    dst = W2p + (size_t)idx * 512;
    fbase = 32 * kc + 8 * hi; obase = 16 * cb + lo;
  } else {
    int idx = w - 1728;
    int kc = idx >> 4, cb = idx & 15;
    src = Wsk;
    dst = Wsp + (size_t)idx * 512;
    fbase = 32 * kc + 8 * hi; obase = 16 * cb + lo;
  }
  bf16x8 v;
#pragma unroll
  for (int j = 0; j < 8; ++j)
    v[j] = (bf16_t)src[(fbase + j) * 256 + obase];
  *(bf16x8*)(dst + l * 8) = v;
}

// ---------------- GN1 stats: sum/sumsq per (vt, group of 4 ch) ----------------
__global__ void gn1_stats(const float* __restrict__ x,
                          float* __restrict__ sum1, float* __restrict__ ss1) {
  int vt = blockIdx.y;
  int s0 = blockIdx.x * 256;
  int t = threadIdx.x;
  int col = t & 31, ro = t >> 5;           // col = float4 index = group
  float s_ = 0.f, q_ = 0.f;
  const f32x4* xp = (const f32x4*)(x + ((size_t)vt * S_TOT + s0) * F_IN);
#pragma unroll 4
  for (int it = 0; it < 32; ++it) {
    f32x4 v = xp[(size_t)(it * 8 + ro) * 32 + col];
    s_ += v[0] + v[1] + v[2] + v[3];
    q_ += v[0]*v[0] + v[1]*v[1] + v[2]*v[2] + v[3]*v[3];
  }
  __shared__ float gs[32], gq[32];
  if (t < 32) { gs[t] = 0.f; gq[t] = 0.f; }
  __syncthreads();
  atomicAdd(&gs[col], s_);
  atomicAdd(&gq[col], q_);
  __syncthreads();
  if (t < 32) {
    atomicAdd(&sum1[vt * 32 + t], gs[t]);
    atomicAdd(&ss1[vt * 32 + t], gq[t]);
  }
}

__global__ void fin_gn1(const float* __restrict__ sum1, const float* __restrict__ ss1,
                        const float* __restrict__ gs, const float* __restrict__ gb,
                        float* __restrict__ a1, float* __restrict__ b1a) {
  int t = threadIdx.x;              // 512 = 4 vt * 128 ch
  int vt = t >> 7, c = t & 127, g = c >> 2;
  float N = (float)(S_TOT * 4);
  float mean = sum1[vt * 32 + g] / N;
  float var = ss1[vt * 32 + g] / N - mean * mean;
  float r = rsqrtf(var + EPS);
  float a = r * gs[c];
  a1[t] = a;
  b1a[t] = gb[c] - mean * a;
}

__global__ void fin_gn2(const float* __restrict__ sum_c, const float* __restrict__ ss_c,
                        const float* __restrict__ gs, const float* __restrict__ gb,
                        float* __restrict__ a2, float* __restrict__ b2a) {
  int t = threadIdx.x;              // 1024 = 4 vt * 256 ch
  int vt = t >> 8, c = t & 255, g = c >> 3;
  float sg = 0.f, qg = 0.f;
#pragma unroll
  for (int j = 0; j < 8; ++j) {
    sg += sum_c[vt * 256 + g * 8 + j];
    qg += ss_c[vt * 256 + g * 8 + j];
  }
  float N = (float)(S_TOT * 8);
  float mean = sg / N;
  float var = qg / N - mean * mean;
  float r = rsqrtf(var + EPS);
  float a = r * gs[c];
  a2[t] = a;
  b2a[t] = gb[c] - mean * a;
}

// ---------------- apply GN1 affine + SiLU -> h1 (bf16) ----------------
__global__ void apply_gn1(const float* __restrict__ x, const float* __restrict__ a,
                          const float* __restrict__ b, bf16_t* __restrict__ h1) {
  size_t base = ((size_t)blockIdx.x * 256 + threadIdx.x) * 8;
  int vt = (int)(base / ((size_t)S_TOT * F_IN));
  int c0 = (int)(base & (F_IN - 1));
  const f32x4* xp = (const f32x4*)(x + base);
  f32x4 v0 = xp[0], v1 = xp[1];
  const f32x4* ap = (const f32x4*)(a + vt * F_IN + c0);
  const f32x4* bp = (const f32x4*)(b + vt * F_IN + c0);
  f32x4 A0 = ap[0], A1 = ap[1], B0 = bp[0], B1 = bp[1];
  bf16x8 o;
#pragma unroll
  for (int j = 0; j < 4; ++j) o[j] = (bf16_t)silu_f(v0[j] * A0[j] + B0[j]);
#pragma unroll
  for (int j = 0; j < 4; ++j) o[4 + j] = (bf16_t)silu_f(v1[j] * A1[j] + B1[j]);
  *(bf16x8*)(h1 + base) = o;
}

// ---------------- apply GN2 affine + SiLU in place (bf16) ----------------
__global__ void apply_gn2(bf16_t* __restrict__ h, const float* __restrict__ a,
                          const float* __restrict__ b) {
  size_t base = ((size_t)blockIdx.x * 256 + threadIdx.x) * 8;
  int vt = (int)(base / ((size_t)S_TOT * F_OUT));
  int c0 = (int)(base & (F_OUT - 1));
  bf16x8 v = *(const bf16x8*)(h + base);
  const f32x4* ap = (const f32x4*)(a + vt * F_OUT + c0);
  const f32x4* bp = (const f32x4*)(b + vt * F_OUT + c0);
  f32x4 A0 = ap[0], A1 = ap[1], B0 = bp[0], B1 = bp[1];
  bf16x8 o;
#pragma unroll
  for (int j = 0; j < 4; ++j) o[j] = (bf16_t)silu_f((float)v[j] * A0[j] + B0[j]);
#pragma unroll
  for (int j = 0; j < 4; ++j) o[4 + j] = (bf16_t)silu_f((float)v[4 + j] * A1[j] + B1[j]);
  *(bf16x8*)(h + base) = o;
}

// ---------------- conv1: out1[s,o] = b1[o] + sum_k sum_f h1[adj[s,k],f] W1[k,f,o]
// 64x256 tile, 4 waves (wave w covers cols 64w..64w+63), K = 9 * 128.
// Fused GN2 per-channel sum/sumsq via shfl + atomics.
__global__ __launch_bounds__(256, 2) void conv1_kernel(
    const bf16_t* __restrict__ h1, const bf16_t* __restrict__ W1p,
    const int* __restrict__ adjc, const float* __restrict__ bias1,
    bf16_t* __restrict__ out1, float* __restrict__ sum_c, float* __restrict__ ss_c) {
  const int vt = blockIdx.y;
  const int s0 = blockIdx.x * 64;
  const int tid = threadIdx.x;
  const int wv = tid >> 6, l = tid & 63;
  const int lo = l & 15, hi = l >> 4;

  __shared__ int adj[576];
  __shared__ bf16_t abuf[2][64 * 128];   // seg16-XOR-swizzled rows

  for (int i = tid; i < 576; i += 256) adj[i] = adjc[s0 * 9 + i];
  __syncthreads();

  const int r = tid >> 2, q = tid & 3;   // r = row 0..63, q covers 64B
  const bf16_t* hbase = h1 + (size_t)vt * S_TOT * F_IN;

  bf16x8 st[4];
  {
    const bf16_t* rp = hbase + (size_t)adj[r * 9 + 0] * F_IN;
#pragma unroll
    for (int i = 0; i < 4; ++i) st[i] = *(const bf16x8*)(rp + (q * 4 + i) * 8);
#pragma unroll
    for (int i = 0; i < 4; ++i) {
      int seg = q * 4 + i;
      *(bf16x8*)(&abuf[0][r * 128 + ((seg ^ (r & 7)) * 8)]) = st[i];
    }
  }
  __syncthreads();

  f32x4 acc[4][4] = {};
  for (int k = 0; k < 9; ++k) {
    int cur = k & 1;
    if (k < 8) {
      const bf16_t* rp = hbase + (size_t)adj[r * 9 + k + 1] * F_IN;
#pragma unroll
      for (int i = 0; i < 4; ++i) st[i] = *(const bf16x8*)(rp + (q * 4 + i) * 8);
    }
#pragma unroll
    for (int kc = 0; kc < 4; ++kc) {
      bf16x8 bfr[4];
      const bf16_t* wb = W1p + (size_t)((k * 4 + kc) * 16) * 512;
#pragma unroll
      for (int ni = 0; ni < 4; ++ni)
        bfr[ni] = *(const bf16x8*)(wb + (size_t)(wv * 4 + ni) * 512 + l * 8);
      bf16x8 afr[4];
      int seg = 4 * kc + hi;
#pragma unroll
      for (int mi = 0; mi < 4; ++mi) {
        int rr = mi * 16 + lo;
        afr[mi] = *(const bf16x8*)(&abuf[cur][rr * 128 + ((seg ^ (rr & 7)) * 8)]);
      }
#pragma unroll
      for (int mi = 0; mi < 4; ++mi)
#pragma unroll
        for (int ni = 0; ni < 4; ++ni)
          acc[mi][ni] = __builtin_amdgcn_mfma_f32_16x16x32_bf16(afr[mi], bfr[ni], acc[mi][ni], 0, 0, 0);
    }
    if (k < 8) {
#pragma unroll
      for (int i = 0; i < 4; ++i) {
        int seg = q * 4 + i;
        *(bf16x8*)(&abuf[cur ^ 1][r * 128 + ((seg ^ (r & 7)) * 8)]) = st[i];
      }
    }
    __syncthreads();
  }

  bf16_t* obase = out1 + ((size_t)vt * S_TOT + s0) * F_OUT;
#pragma unroll
  for (int ni = 0; ni < 4; ++ni) {
    int o = wv * 64 + ni * 16 + lo;
    float bv = bias1[o];
    float s_ = 0.f, q_ = 0.f;
#pragma unroll
    for (int mi = 0; mi < 4; ++mi)
#pragma unroll
      for (int rr2 = 0; rr2 < 4; ++rr2) {
        int srow = mi * 16 + hi * 4 + rr2;
        float v = acc[mi][ni][rr2] + bv;
        obase[(size_t)srow * F_OUT + o] = (bf16_t)v;
        s_ += v; q_ += v * v;
      }
    s_ += __shfl_xor(s_, 16); s_ += __shfl_xor(s_, 32);
    q_ += __shfl_xor(q_, 16); q_ += __shfl_xor(q_, 32);
    if (hi == 0) {
      atomicAdd(&sum_c[vt * F_OUT + o], s_);
      atomicAdd(&ss_c[vt * F_OUT + o], q_);
    }
  }
}

// ---------------- conv2 + fused skip GEMM + biases -> f32 out ----------------
// ks=0..8: gathered h2 (K=256 each); ks=9: direct x (K=128) with W_skip.
__global__ __launch_bounds__(256, 2) void conv2_kernel(
    const bf16_t* __restrict__ h2, const bf16_t* __restrict__ W2p,
    const bf16_t* __restrict__ Wsp, const float* __restrict__ x,
    const int* __restrict__ adjc, const float* __restrict__ bias2,
    const float* __restrict__ biask, float* __restrict__ out) {
  const int vt = blockIdx.y;
  const int s0 = blockIdx.x * 64;
  const int tid = threadIdx.x;
  const int wv = tid >> 6, l = tid & 63;
  const int lo = l & 15, hi = l >> 4;

  __shared__ int adj[576];
  __shared__ bf16_t abuf[2][64 * 256];

  for (int i = tid; i < 576; i += 256) adj[i] = adjc[s0 * 9 + i];
  __syncthreads();

  const int r = tid >> 2, q = tid & 3;   // q covers 128B of the 512B row
  const bf16_t* hbase = h2 + (size_t)vt * S_TOT * F_OUT;
  const float* xbase = x + ((size_t)vt * S_TOT + s0) * F_IN;

  bf16x8 st[8];
  {
    const bf16_t* rp = hbase + (size_t)adj[r * 9 + 0] * F_OUT;
#pragma unroll
    for (int i = 0; i < 8; ++i) st[i] = *(const bf16x8*)(rp + (q * 8 + i) * 8);
#pragma unroll
    for (int i = 0; i < 8; ++i) {
      int seg = q * 8 + i;
      *(bf16x8*)(&abuf[0][r * 256 + ((seg ^ (r & 7)) * 8)]) = st[i];
    }
  }
  __syncthreads();

  f32x4 acc[4][4] = {};
  for (int ks = 0; ks < 10; ++ks) {
    int cur = ks & 1;
    f32x4 xr[8];
    if (ks < 8) {
      const bf16_t* rp = hbase + (size_t)adj[r * 9 + ks + 1] * F_OUT;
#pragma unroll
      for (int i = 0; i < 8; ++i) st[i] = *(const bf16x8*)(rp + (q * 8 + i) * 8);
    } else if (ks == 8) {
      const float* rp = xbase + (size_t)r * F_IN;
#pragma unroll
      for (int i = 0; i < 8; ++i)
        xr[i] = *(const f32x4*)(rp + (q * 4 + (i >> 1)) * 8 + (i & 1) * 4);
    }
    if (ks < 9) {
      const bf16_t* wpk = W2p + (size_t)(ks * 8) * 16 * 512;
#pragma unroll
      for (int kc = 0; kc < 8; ++kc) {
        bf16x8 bfr[4];
        const bf16_t* wb = wpk + (size_t)(kc * 16) * 512;
#pragma unroll
        for (int ni = 0; ni < 4; ++ni)
          bfr[ni] = *(const bf16x8*)(wb + (size_t)(wv * 4 + ni) * 512 + l * 8);
        bf16x8 afr[4];
        int seg = 4 * kc + hi;
#pragma unroll
        for (int mi = 0; mi < 4; ++mi) {
          int rr = mi * 16 + lo;
          afr[mi] = *(const bf16x8*)(&abuf[cur][rr * 256 + ((seg ^ (rr & 7)) * 8)]);
        }
#pragma unroll
        for (int mi = 0; mi < 4; ++mi)
#pragma unroll
          for (int ni = 0; ni < 4; ++ni)
            acc[mi][ni] = __builtin_amdgcn_mfma_f32_16x16x32_bf16(afr[mi], bfr[ni], acc[mi][ni], 0, 0, 0);
      }
    } else {
#pragma unroll
      for (int kc = 0; kc < 4; ++kc) {
        bf16x8 bfr[4];
        const bf16_t* wb = Wsp + (size_t)(kc * 16) * 512;
#pragma unroll
        for (int ni = 0; ni < 4; ++ni)
          bfr[ni] = *(const bf16x8*)(wb + (size_t)(wv * 4 + ni) * 512 + l * 8);
        bf16x8 afr[4];
        int seg = 4 * kc + hi;
#pragma unroll
        for (int mi = 0; mi < 4; ++mi) {
          int rr = mi * 16 + lo;
          afr[mi] = *(const bf16x8*)(&abuf[cur][rr * 256 + ((seg ^ (rr & 7)) * 8)]);
        }
#pragma unroll
        for (int mi = 0; mi < 4; ++mi)
#pragma unroll
          for (int ni = 0; ni < 4; ++ni)
            acc[mi][ni] = __builtin_amdgcn_mfma_f32_16x16x32_bf16(afr[mi], bfr[ni], acc[mi][ni], 0, 0, 0);
      }
    }
    if (ks < 8) {
#pragma unroll
      for (int i = 0; i < 8; ++i) {
        int seg = q * 8 + i;
        *(bf16x8*)(&abuf[cur ^ 1][r * 256 + ((seg ^ (r & 7)) * 8)]) = st[i];
      }
    } else if (ks == 8) {
#pragma unroll
      for (int i = 0; i < 4; ++i) {
        bf16x8 w;
        f32x4 v0 = xr[i * 2], v1 = xr[i * 2 + 1];
#pragma unroll
        for (int j = 0; j < 4; ++j) { w[j] = (bf16_t)v0[j]; w[4 + j] = (bf16_t)v1[j]; }
        int seg = q * 4 + i;
        *(bf16x8*)(&abuf[cur ^ 1][r * 256 + ((seg ^ (r & 7)) * 8)]) = w;
      }
    }
    __syncthreads();
  }

  float* obase = out + ((size_t)vt * S_TOT + s0) * F_OUT;
#pragma unroll
  for (int ni = 0; ni < 4; ++ni) {
    int o = wv * 64 + ni * 16 + lo;
    float bv = bias2[o] + biask[o];
#pragma unroll
    for (int mi = 0; mi < 4; ++mi)
#pragma unroll
      for (int rr2 = 0; rr2 < 4; ++rr2) {
        int srow = mi * 16 + hi * 4 + rr2;
        obase[(size_t)srow * F_OUT + o] = acc[mi][ni][rr2] + bv;
      }
  }
}

extern "C" void kernel_launch(void* const* d_in, const int* in_sizes, int n_in,
                              void* d_out, int out_size, void* d_ws, size_t ws_size,
                              hipStream_t stream) {
  const float* x      = (const float*)d_in[0];
  const int*   adjc   = (const int*)d_in[1];
  const float* gn1_s  = (const float*)d_in[2];
  const float* gn1_b  = (const float*)d_in[3];
  const float* gn2_s  = (const float*)d_in[4];
  const float* gn2_b  = (const float*)d_in[5];
  const float* W_skip = (const float*)d_in[6];
  const float* b_skip = (const float*)d_in[7];
  const float* W1     = (const float*)d_in[8];
  const float* b1     = (const float*)d_in[9];
  const float* W2     = (const float*)d_in[10];
  const float* b2     = (const float*)d_in[11];
  float* out = (float*)d_out;

  float* sum1  = (float*)d_ws;           // 128
  float* ss1   = sum1 + 128;             // 128
  float* sum_c = ss1 + 128;              // 1024
  float* ss_c  = sum_c + 1024;           // 1024
  float* a1    = ss_c + 1024;            // 512
  float* b1a   = a1 + 512;               // 512
  float* a2    = b1a + 512;              // 1024
  float* b2a   = a2 + 1024;              // 1024
  bf16_t* W1p  = (bf16_t*)(b2a + 1024);  // 294912
  bf16_t* W2p  = W1p + 294912;           // 589824
  bf16_t* Wsp  = W2p + 589824;           // 32768
  bf16_t* h1   = Wsp + 32768;            // 6291456
  bf16_t* out1 = h1 + 6291456;           // 12582912 (reused in place as h2)

  hipMemsetAsync(sum1, 0, (128 + 128 + 1024 + 1024) * sizeof(float), stream);
  pack_weights<<<448, 256, 0, stream>>>(W1, W2, W_skip, W1p, W2p, Wsp);
  gn1_stats<<<dim3(48, 4), 256, 0, stream>>>(x, sum1, ss1);
  fin_gn1<<<1, 512, 0, stream>>>(sum1, ss1, gn1_s, gn1_b, a1, b1a);
  apply_gn1<<<3072, 256, 0, stream>>>(x, a1, b1a, h1);
  conv1_kernel<<<dim3(192, 4), 256, 0, stream>>>(h1, W1p, adjc, b1, out1, sum_c, ss_c);
  fin_gn2<<<1, 1024, 0, stream>>>(sum_c, ss_c, gn2_s, gn2_b, a2, b2a);
  apply_gn2<<<6144, 256, 0, stream>>>(out1, a2, b2a);
  conv2_kernel<<<dim3(192, 4), 256, 0, stream>>>(out1, W2p, Wsp, x, adjc, b2, b_skip, out);
}

// Round 2
// 191.620 us; speedup vs baseline: 1.0547x; 1.0547x over previous
//
#include <hip/hip_runtime.h>
#include <hip/hip_bf16.h>

typedef __bf16 bf16_t;
typedef __bf16 bf16x8 __attribute__((ext_vector_type(8)));
typedef float f32x4 __attribute__((ext_vector_type(4)));

#define S_TOT 12288
#define F_IN 128
#define F_OUT 256
#define EPS 1e-5f

static __device__ __forceinline__ float silu_f(float v) {
  return v / (1.0f + __expf(-v));
}

static __device__ __forceinline__ void gll16(const bf16_t* g, bf16_t* l) {
  __builtin_amdgcn_global_load_lds(
      (const __attribute__((address_space(1))) void*)(const void*)g,
      (__attribute__((address_space(3))) void*)(void*)l, 16, 0, 0);
}

// ---------------- pack weights into MFMA B-frag order ----------------
// Unit = (k, kc, cb): lane l holds B[f=32kc+8*(l>>4)+j][o=16cb+(l&15)]
// stored at unit*1024B + l*16B. W1: 9*4*16=576 units; W2: 9*8*16=1152; Wsk: 4*16=64.
__global__ void pack_weights(const float* __restrict__ W1,
                             const float* __restrict__ W2,
                             const float* __restrict__ Wsk,
                             bf16_t* __restrict__ W1p,
                             bf16_t* __restrict__ W2p,
                             bf16_t* __restrict__ Wsp) {
  int w = blockIdx.x * 4 + (threadIdx.x >> 6);
  int l = threadIdx.x & 63;
  int lo = l & 15, hi = l >> 4;
  const float* src;
  bf16_t* dst;
  int fbase, obase;
  if (w < 576) {
    int k = w >> 6, rem = w & 63, kc = rem >> 4, cb = rem & 15;
    src = W1 + k * 32768;
    dst = W1p + (size_t)w * 512;
    fbase = 32 * kc + 8 * hi; obase = 16 * cb + lo;
  } else if (w < 1728) {
    int idx = w - 576;
    int k = idx >> 7, rem = idx & 127, kc = rem >> 4, cb = rem & 15;
    src = W2 + k * 65536;
    dst = W2p + (size_t)idx * 512;
    fbase = 32 * kc + 8 * hi; obase = 16 * cb + lo;
  } else {
    int idx = w - 1728;
    int kc = idx >> 4, cb = idx & 15;
    src = Wsk;
    dst = Wsp + (size_t)idx * 512;
    fbase = 32 * kc + 8 * hi; obase = 16 * cb + lo;
  }
  bf16x8 v;
#pragma unroll
  for (int j = 0; j < 8; ++j)
    v[j] = (bf16_t)src[(fbase + j) * 256 + obase];
  *(bf16x8*)(dst + l * 8) = v;
}

// ---------------- GN1 stats ----------------
__global__ void gn1_stats(const float* __restrict__ x,
                          float* __restrict__ sum1, float* __restrict__ ss1) {
  int vt = blockIdx.y;
  int s0 = blockIdx.x * 256;
  int t = threadIdx.x;
  int col = t & 31, ro = t >> 5;
  float s_ = 0.f, q_ = 0.f;
  const f32x4* xp = (const f32x4*)(x + ((size_t)vt * S_TOT + s0) * F_IN);
#pragma unroll 4
  for (int it = 0; it < 32; ++it) {
    f32x4 v = xp[(size_t)(it * 8 + ro) * 32 + col];
    s_ += v[0] + v[1] + v[2] + v[3];
    q_ += v[0]*v[0] + v[1]*v[1] + v[2]*v[2] + v[3]*v[3];
  }
  __shared__ float gs[32], gq[32];
  if (t < 32) { gs[t] = 0.f; gq[t] = 0.f; }
  __syncthreads();
  atomicAdd(&gs[col], s_);
  atomicAdd(&gq[col], q_);
  __syncthreads();
  if (t < 32) {
    atomicAdd(&sum1[vt * 32 + t], gs[t]);
    atomicAdd(&ss1[vt * 32 + t], gq[t]);
  }
}

__global__ void fin_gn1(const float* __restrict__ sum1, const float* __restrict__ ss1,
                        const float* __restrict__ gs, const float* __restrict__ gb,
                        float* __restrict__ a1, float* __restrict__ b1a) {
  int t = threadIdx.x;
  int vt = t >> 7, c = t & 127, g = c >> 2;
  float N = (float)(S_TOT * 4);
  float mean = sum1[vt * 32 + g] / N;
  float var = ss1[vt * 32 + g] / N - mean * mean;
  float r = rsqrtf(var + EPS);
  float a = r * gs[c];
  a1[t] = a;
  b1a[t] = gb[c] - mean * a;
}

__global__ void fin_gn2(const float* __restrict__ sum_c, const float* __restrict__ ss_c,
                        const float* __restrict__ gs, const float* __restrict__ gb,
                        float* __restrict__ a2, float* __restrict__ b2a) {
  int t = threadIdx.x;
  int vt = t >> 8, c = t & 255, g = c >> 3;
  float sg = 0.f, qg = 0.f;
#pragma unroll
  for (int j = 0; j < 8; ++j) {
    sg += sum_c[vt * 256 + g * 8 + j];
    qg += ss_c[vt * 256 + g * 8 + j];
  }
  float N = (float)(S_TOT * 8);
  float mean = sg / N;
  float var = qg / N - mean * mean;
  float r = rsqrtf(var + EPS);
  float a = r * gs[c];
  a2[t] = a;
  b2a[t] = gb[c] - mean * a;
}

// ---------------- apply GN1 affine + SiLU -> h1 (bf16) ----------------
__global__ void apply_gn1(const float* __restrict__ x, const float* __restrict__ a,
                          const float* __restrict__ b, bf16_t* __restrict__ h1) {
  size_t base = ((size_t)blockIdx.x * 256 + threadIdx.x) * 8;
  int vt = (int)(base / ((size_t)S_TOT * F_IN));
  int c0 = (int)(base & (F_IN - 1));
  const f32x4* xp = (const f32x4*)(x + base);
  f32x4 v0 = xp[0], v1 = xp[1];
  const f32x4* ap = (const f32x4*)(a + vt * F_IN + c0);
  const f32x4* bp = (const f32x4*)(b + vt * F_IN + c0);
  f32x4 A0 = ap[0], A1 = ap[1], B0 = bp[0], B1 = bp[1];
  bf16x8 o;
#pragma unroll
  for (int j = 0; j < 4; ++j) o[j] = (bf16_t)silu_f(v0[j] * A0[j] + B0[j]);
#pragma unroll
  for (int j = 0; j < 4; ++j) o[4 + j] = (bf16_t)silu_f(v1[j] * A1[j] + B1[j]);
  *(bf16x8*)(h1 + base) = o;
}

// ---------------- apply GN2 affine + SiLU in place (bf16) ----------------
__global__ void apply_gn2(bf16_t* __restrict__ h, const float* __restrict__ a,
                          const float* __restrict__ b) {
  size_t base = ((size_t)blockIdx.x * 256 + threadIdx.x) * 8;
  int vt = (int)(base / ((size_t)S_TOT * F_OUT));
  int c0 = (int)(base & (F_OUT - 1));
  bf16x8 v = *(const bf16x8*)(h + base);
  const f32x4* ap = (const f32x4*)(a + vt * F_OUT + c0);
  const f32x4* bp = (const f32x4*)(b + vt * F_OUT + c0);
  f32x4 A0 = ap[0], A1 = ap[1], B0 = bp[0], B1 = bp[1];
  bf16x8 o;
#pragma unroll
  for (int j = 0; j < 4; ++j) o[j] = (bf16_t)silu_f((float)v[j] * A0[j] + B0[j]);
#pragma unroll
  for (int j = 0; j < 4; ++j) o[4 + j] = (bf16_t)silu_f((float)v[4 + j] * A1[j] + B1[j]);
  *(bf16x8*)(h + base) = o;
}

// ---------------- unified gather-conv GEMM ----------------
// Tile M=128 x N=128 (nsp selects col half), 512 threads = 8 waves of 32rows x 64cols.
// K substages of 128; A staged via global_load_lds with XOR-preswizzled gather source.
// RE = source row elements (128 for conv1/h1, 256 for conv2/h2).
template<int RE, int NSUB, bool XSTAGE>
__global__ __launch_bounds__(512, 4) void conv_kernel(
    const bf16_t* __restrict__ hsrc, const bf16_t* __restrict__ Wp,
    const bf16_t* __restrict__ Wsp, const float* __restrict__ x,
    const int* __restrict__ adjc, const float* __restrict__ bias,
    const float* __restrict__ biask, bf16_t* __restrict__ outb,
    float* __restrict__ outf, float* __restrict__ sum_c, float* __restrict__ ss_c) {
  const int tid = threadIdx.x;
  const int wv = tid >> 6, l = tid & 63;
  const int lo = l & 15, hi = l >> 4;
  const int mw = wv >> 1, nw = wv & 1;

  int swz = ((blockIdx.x & 7) * 96) + (blockIdx.x >> 3);   // bijective: 768 = 8*96
  int vt = swz / 192;
  int rem = swz - vt * 192;
  int sblk = rem >> 1, nsp = rem & 1;
  int s0 = sblk * 128;

  __shared__ int adjs[1152];
  __shared__ bf16_t ab[2][16384];   // 2 x 128 rows x 128 bf16 (seg16-XOR swizzled)

  for (int i = tid; i < 1152; i += 512) adjs[i] = adjc[s0 * 9 + i];
  __syncthreads();

  const bf16_t* hb = hsrc + (size_t)vt * ((size_t)S_TOT * RE);

  // stage substage s into ab[buf]: 32 x global_load_lds(16B), 4 per wave.
  // instr j covers rows 4j..4j+3 (256B each). lane l -> row 4j+(l>>4), lds seg l&15.
  // source seg pre-swizzled so LDS[row][s] = src[row][s ^ (row&7)].
  auto stage = [&](int buf, int s) {
    int k = (RE == 256) ? (s >> 1) : s;
    int h = (RE == 256) ? (s & 1) : 0;
#pragma unroll
    for (int j2 = 0; j2 < 4; ++j2) {
      int j = wv * 4 + j2;
      int row = 4 * j + hi;
      int arow = adjs[row * 9 + k];
      const bf16_t* g = hb + (size_t)arow * RE + h * 128 + ((lo ^ (row & 7)) << 3);
      gll16(g, &ab[buf][j * 512]);
    }
  };

  f32x4 acc[2][4] = {};
  auto compute = [&](int buf, const bf16_t* wbase, int ub) {
#pragma unroll
    for (int kc = 0; kc < 4; ++kc) {
      bf16x8 bfr[4];
      const bf16_t* wb = wbase + ((size_t)((ub + kc) * 16 + nsp * 8 + nw * 4)) * 512 + l * 8;
#pragma unroll
      for (int ni = 0; ni < 4; ++ni)
        bfr[ni] = *(const bf16x8*)(wb + ni * 512);
      int seg = 4 * kc + hi;
      bf16x8 afr[2];
#pragma unroll
      for (int mi = 0; mi < 2; ++mi) {
        int rr = mw * 32 + mi * 16 + lo;
        afr[mi] = *(const bf16x8*)(&ab[buf][rr * 128 + ((seg ^ (lo & 7)) << 3)]);
      }
#pragma unroll
      for (int mi = 0; mi < 2; ++mi)
#pragma unroll
        for (int ni = 0; ni < 4; ++ni)
          acc[mi][ni] = __builtin_amdgcn_mfma_f32_16x16x32_bf16(afr[mi], bfr[ni], acc[mi][ni], 0, 0, 0);
    }
  };

  stage(0, 0);
  __syncthreads();

  for (int s = 0; s < NSUB; ++s) {
    int buf = s & 1;
    if (s + 1 < NSUB) {
      stage(buf ^ 1, s + 1);
    } else if (XSTAGE) {
      // stage x (f32 -> bf16) into buf^1 via registers (needs convert; no gll)
      int row = tid >> 2, q = tid & 3;
      const float* xr = x + ((size_t)vt * S_TOT + s0 + row) * 128 + q * 32;
      f32x4 xv[8];
#pragma unroll
      for (int i = 0; i < 8; ++i) xv[i] = *(const f32x4*)(xr + i * 4);
#pragma unroll
      for (int i = 0; i < 4; ++i) {
        bf16x8 w;
#pragma unroll
        for (int jj = 0; jj < 4; ++jj) {
          w[jj] = (bf16_t)xv[2 * i][jj];
          w[4 + jj] = (bf16_t)xv[2 * i + 1][jj];
        }
        int seg = q * 4 + i;
        *(bf16x8*)(&ab[buf ^ 1][row * 128 + ((seg ^ (row & 7)) << 3)]) = w;
      }
    }
    compute(buf, Wp, s * 4);
    __syncthreads();
  }
  if (XSTAGE) compute(NSUB & 1, Wsp, 0);

  if (!XSTAGE) {
    bf16_t* ob = outb + ((size_t)vt * S_TOT + s0) * 256;
#pragma unroll
    for (int mi = 0; mi < 2; ++mi)
#pragma unroll
      for (int ni = 0; ni < 4; ++ni) {
        int o = nsp * 128 + nw * 64 + ni * 16 + lo;
        float bv = bias[o];
        float s_ = 0.f, q_ = 0.f;
#pragma unroll
        for (int r2 = 0; r2 < 4; ++r2) {
          int srow = mw * 32 + mi * 16 + hi * 4 + r2;
          float v = acc[mi][ni][r2] + bv;
          ob[(size_t)srow * 256 + o] = (bf16_t)v;
          s_ += v; q_ += v * v;
        }
        s_ += __shfl_xor(s_, 16); s_ += __shfl_xor(s_, 32);
        q_ += __shfl_xor(q_, 16); q_ += __shfl_xor(q_, 32);
        if (hi == 0) {
          atomicAdd(&sum_c[vt * 256 + o], s_);
          atomicAdd(&ss_c[vt * 256 + o], q_);
        }
      }
  } else {
    float* of = outf + ((size_t)vt * S_TOT + s0) * 256;
#pragma unroll
    for (int mi = 0; mi < 2; ++mi)
#pragma unroll
      for (int ni = 0; ni < 4; ++ni) {
        int o = nsp * 128 + nw * 64 + ni * 16 + lo;
        float bv = bias[o] + biask[o];
#pragma unroll
        for (int r2 = 0; r2 < 4; ++r2) {
          int srow = mw * 32 + mi * 16 + hi * 4 + r2;
          of[(size_t)srow * 256 + o] = acc[mi][ni][r2] + bv;
        }
      }
  }
}

extern "C" void kernel_launch(void* const* d_in, const int* in_sizes, int n_in,
                              void* d_out, int out_size, void* d_ws, size_t ws_size,
                              hipStream_t stream) {
  const float* x      = (const float*)d_in[0];
  const int*   adjc   = (const int*)d_in[1];
  const float* gn1_s  = (const float*)d_in[2];
  const float* gn1_b  = (const float*)d_in[3];
  const float* gn2_s  = (const float*)d_in[4];
  const float* gn2_b  = (const float*)d_in[5];
  const float* W_skip = (const float*)d_in[6];
  const float* b_skip = (const float*)d_in[7];
  const float* W1     = (const float*)d_in[8];
  const float* b1     = (const float*)d_in[9];
  const float* W2     = (const float*)d_in[10];
  const float* b2     = (const float*)d_in[11];
  float* out = (float*)d_out;

  float* sum1  = (float*)d_ws;           // 128
  float* ss1   = sum1 + 128;             // 128
  float* sum_c = ss1 + 128;              // 1024
  float* ss_c  = sum_c + 1024;           // 1024
  float* a1    = ss_c + 1024;            // 512
  float* b1a   = a1 + 512;               // 512
  float* a2    = b1a + 512;              // 1024
  float* b2a   = a2 + 1024;              // 1024
  bf16_t* W1p  = (bf16_t*)(b2a + 1024);  // 294912
  bf16_t* W2p  = W1p + 294912;           // 589824
  bf16_t* Wsp  = W2p + 589824;           // 32768
  bf16_t* h1   = Wsp + 32768;            // 6291456
  bf16_t* out1 = h1 + 6291456;           // 12582912 (reused in place as h2)

  hipMemsetAsync(sum1, 0, (128 + 128 + 1024 + 1024) * sizeof(float), stream);
  pack_weights<<<448, 256, 0, stream>>>(W1, W2, W_skip, W1p, W2p, Wsp);
  gn1_stats<<<dim3(48, 4), 256, 0, stream>>>(x, sum1, ss1);
  fin_gn1<<<1, 512, 0, stream>>>(sum1, ss1, gn1_s, gn1_b, a1, b1a);
  apply_gn1<<<3072, 256, 0, stream>>>(x, a1, b1a, h1);
  conv_kernel<128, 9, false><<<768, 512, 0, stream>>>(
      h1, W1p, nullptr, nullptr, adjc, b1, nullptr, out1, nullptr, sum_c, ss_c);
  fin_gn2<<<1, 1024, 0, stream>>>(sum_c, ss_c, gn2_s, gn2_b, a2, b2a);
  apply_gn2<<<6144, 256, 0, stream>>>(out1, a2, b2a);
  conv_kernel<256, 18, true><<<768, 512, 0, stream>>>(
      out1, W2p, Wsp, x, adjc, b2, b_skip, nullptr, out, nullptr, nullptr);
}

// Round 3
// 190.065 us; speedup vs baseline: 1.0633x; 1.0082x over previous
//
#include <hip/hip_runtime.h>
#include <hip/hip_bf16.h>

typedef __bf16 bf16_t;
typedef __bf16 bf16x8 __attribute__((ext_vector_type(8)));
typedef float f32x4 __attribute__((ext_vector_type(4)));

#define S_TOT 12288
#define F_IN 128
#define F_OUT 256
#define EPS 1e-5f

static __device__ __forceinline__ float silu_f(float v) {
  return v / (1.0f + __expf(-v));
}

static __device__ __forceinline__ void gll16(const bf16_t* g, bf16_t* l) {
  __builtin_amdgcn_global_load_lds(
      (const __attribute__((address_space(1))) void*)(const void*)g,
      (__attribute__((address_space(3))) void*)(void*)l, 16, 0, 0);
}

// ---------------- pack weights into MFMA B-frag order ----------------
// Unit = (k, kc, cb): lane l holds B[f=32kc+8*(l>>4)+j][o=16cb+(l&15)]
// stored at unit*1024B + l*16B. W1: 9*4*16=576 units; W2: 9*8*16=1152; Wsk: 4*16=64.
__global__ void pack_weights(const float* __restrict__ W1,
                             const float* __restrict__ W2,
                             const float* __restrict__ Wsk,
                             bf16_t* __restrict__ W1p,
                             bf16_t* __restrict__ W2p,
                             bf16_t* __restrict__ Wsp) {
  int w = blockIdx.x * 4 + (threadIdx.x >> 6);
  int l = threadIdx.x & 63;
  int lo = l & 15, hi = l >> 4;
  const float* src;
  bf16_t* dst;
  int fbase, obase;
  if (w < 576) {
    int k = w >> 6, rem = w & 63, kc = rem >> 4, cb = rem & 15;
    src = W1 + k * 32768;
    dst = W1p + (size_t)w * 512;
    fbase = 32 * kc + 8 * hi; obase = 16 * cb + lo;
  } else if (w < 1728) {
    int idx = w - 576;
    int k = idx >> 7, rem = idx & 127, kc = rem >> 4, cb = rem & 15;
    src = W2 + k * 65536;
    dst = W2p + (size_t)idx * 512;
    fbase = 32 * kc + 8 * hi; obase = 16 * cb + lo;
  } else {
    int idx = w - 1728;
    int kc = idx >> 4, cb = idx & 15;
    src = Wsk;
    dst = Wsp + (size_t)idx * 512;
    fbase = 32 * kc + 8 * hi; obase = 16 * cb + lo;
  }
  bf16x8 v;
#pragma unroll
  for (int j = 0; j < 8; ++j)
    v[j] = (bf16_t)src[(fbase + j) * 256 + obase];
  *(bf16x8*)(dst + l * 8) = v;
}

// ---------------- GN1 stats ----------------
__global__ void gn1_stats(const float* __restrict__ x,
                          float* __restrict__ sum1, float* __restrict__ ss1) {
  int vt = blockIdx.y;
  int s0 = blockIdx.x * 256;
  int t = threadIdx.x;
  int col = t & 31, ro = t >> 5;
  float s_ = 0.f, q_ = 0.f;
  const f32x4* xp = (const f32x4*)(x + ((size_t)vt * S_TOT + s0) * F_IN);
#pragma unroll 4
  for (int it = 0; it < 32; ++it) {
    f32x4 v = xp[(size_t)(it * 8 + ro) * 32 + col];
    s_ += v[0] + v[1] + v[2] + v[3];
    q_ += v[0]*v[0] + v[1]*v[1] + v[2]*v[2] + v[3]*v[3];
  }
  __shared__ float gs[32], gq[32];
  if (t < 32) { gs[t] = 0.f; gq[t] = 0.f; }
  __syncthreads();
  atomicAdd(&gs[col], s_);
  atomicAdd(&gq[col], q_);
  __syncthreads();
  if (t < 32) {
    atomicAdd(&sum1[vt * 32 + t], gs[t]);
    atomicAdd(&ss1[vt * 32 + t], gq[t]);
  }
}

__global__ void fin_gn1(const float* __restrict__ sum1, const float* __restrict__ ss1,
                        const float* __restrict__ gs, const float* __restrict__ gb,
                        float* __restrict__ a1, float* __restrict__ b1a) {
  int t = threadIdx.x;
  int vt = t >> 7, c = t & 127, g = c >> 2;
  float N = (float)(S_TOT * 4);
  float mean = sum1[vt * 32 + g] / N;
  float var = ss1[vt * 32 + g] / N - mean * mean;
  float r = rsqrtf(var + EPS);
  float a = r * gs[c];
  a1[t] = a;
  b1a[t] = gb[c] - mean * a;
}

__global__ void fin_gn2(const float* __restrict__ sum_c, const float* __restrict__ ss_c,
                        const float* __restrict__ gs, const float* __restrict__ gb,
                        float* __restrict__ a2, float* __restrict__ b2a) {
  int t = threadIdx.x;
  int vt = t >> 8, c = t & 255, g = c >> 3;
  float sg = 0.f, qg = 0.f;
#pragma unroll
  for (int j = 0; j < 8; ++j) {
    sg += sum_c[vt * 256 + g * 8 + j];
    qg += ss_c[vt * 256 + g * 8 + j];
  }
  float N = (float)(S_TOT * 8);
  float mean = sg / N;
  float var = qg / N - mean * mean;
  float r = rsqrtf(var + EPS);
  float a = r * gs[c];
  a2[t] = a;
  b2a[t] = gb[c] - mean * a;
}

// ---------------- apply GN1 affine + SiLU -> h1 (bf16) ----------------
__global__ void apply_gn1(const float* __restrict__ x, const float* __restrict__ a,
                          const float* __restrict__ b, bf16_t* __restrict__ h1) {
  size_t base = ((size_t)blockIdx.x * 256 + threadIdx.x) * 8;
  int vt = (int)(base / ((size_t)S_TOT * F_IN));
  int c0 = (int)(base & (F_IN - 1));
  const f32x4* xp = (const f32x4*)(x + base);
  f32x4 v0 = xp[0], v1 = xp[1];
  const f32x4* ap = (const f32x4*)(a + vt * F_IN + c0);
  const f32x4* bp = (const f32x4*)(b + vt * F_IN + c0);
  f32x4 A0 = ap[0], A1 = ap[1], B0 = bp[0], B1 = bp[1];
  bf16x8 o;
#pragma unroll
  for (int j = 0; j < 4; ++j) o[j] = (bf16_t)silu_f(v0[j] * A0[j] + B0[j]);
#pragma unroll
  for (int j = 0; j < 4; ++j) o[4 + j] = (bf16_t)silu_f(v1[j] * A1[j] + B1[j]);
  *(bf16x8*)(h1 + base) = o;
}

// ---------------- apply GN2 affine + SiLU in place (bf16) ----------------
__global__ void apply_gn2(bf16_t* __restrict__ h, const float* __restrict__ a,
                          const float* __restrict__ b) {
  size_t base = ((size_t)blockIdx.x * 256 + threadIdx.x) * 8;
  int vt = (int)(base / ((size_t)S_TOT * F_OUT));
  int c0 = (int)(base & (F_OUT - 1));
  bf16x8 v = *(const bf16x8*)(h + base);
  const f32x4* ap = (const f32x4*)(a + vt * F_OUT + c0);
  const f32x4* bp = (const f32x4*)(b + vt * F_OUT + c0);
  f32x4 A0 = ap[0], A1 = ap[1], B0 = bp[0], B1 = bp[1];
  bf16x8 o;
#pragma unroll
  for (int j = 0; j < 4; ++j) o[j] = (bf16_t)silu_f((float)v[j] * A0[j] + B0[j]);
#pragma unroll
  for (int j = 0; j < 4; ++j) o[4 + j] = (bf16_t)silu_f((float)v[4 + j] * A1[j] + B1[j]);
  *(bf16x8*)(h + base) = o;
}

// ---------------- unified gather-conv GEMM v3 ----------------
// Block tile 128 rows x 128 cols (nsp half), 256 threads = 4 waves of 64x64.
// K-step 64. A gathered via global_load_lds (XOR-preswizzled source);
// B (packed frag-linear weights) ALSO staged via global_load_lds into LDS.
// RE = source row elements (128 conv1, 256 conv2). XSK: 2 extra x-skip steps.
template<int RE, int NSUB, bool XSK>
__global__ __launch_bounds__(256, 2) void conv_kernel(
    const bf16_t* __restrict__ hsrc, const bf16_t* __restrict__ Wp,
    const bf16_t* __restrict__ Wsp, const float* __restrict__ x,
    const int* __restrict__ adjc, const float* __restrict__ bias,
    const float* __restrict__ biask, bf16_t* __restrict__ outb,
    float* __restrict__ outf, float* __restrict__ sum_c, float* __restrict__ ss_c) {
  const int tid = threadIdx.x;
  const int wv = tid >> 6, l = tid & 63;
  const int lo = l & 15, hi = l >> 4;
  const int mw = wv >> 1, nw = wv & 1;

  int swz = ((blockIdx.x & 7) * 96) + (blockIdx.x >> 3);   // bijective: 768 = 8*96
  int vt = swz / 192;
  int rem = swz - vt * 192;
  int sblk = rem >> 1, nsp = rem & 1;
  int s0 = sblk * 128;

  __shared__ int adjs[1152];
  __shared__ bf16_t ab[2][8192];   // 128 rows x 64 cols, seg-XOR swizzled rows
  __shared__ bf16_t bb[2][8192];   // 16 frag-units x 512

  for (int i = tid; i < 1152; i += 256) adjs[i] = adjc[s0 * 9 + i];
  __syncthreads();

  const bf16_t* hb = hsrc + (size_t)vt * ((size_t)S_TOT * RE);
  constexpr int TPK = RE / 64;            // K64-steps per tap
  constexpr int NMAIN = XSK ? (NSUB - 2) : NSUB;

  // A-stage: 16 gll16 (4/wave), instr j covers rows 8j..8j+3.. (8 rows x 128B).
  auto stageA = [&](int buf, int s) {
    int tap = s / TPK, chunk = s % TPK;
#pragma unroll
    for (int j2 = 0; j2 < 4; ++j2) {
      int j = wv * 4 + j2;
      int row = j * 8 + (l >> 3);
      int seg = l & 7;
      int arow = adjs[row * 9 + tap];
      const bf16_t* g = hb + (size_t)arow * RE + chunk * 64 + ((seg ^ (row & 7)) << 3);
      gll16(g, &ab[buf][j * 512]);
    }
  };
  // B-stage: 16 gll16 (4/wave), unit ul = kcl*8 + cb_local, frag-linear.
  auto stageB = [&](int buf, const bf16_t* wsrc, int ubase) {
#pragma unroll
    for (int j2 = 0; j2 < 4; ++j2) {
      int ul = wv * 4 + j2;
      int kcl = ul >> 3, cbl = ul & 7;
      const bf16_t* g = wsrc + ((size_t)((ubase + kcl) * 16 + nsp * 8 + cbl)) * 512 + l * 8;
      gll16(g, &bb[buf][ul * 512]);
    }
  };
  // x-skip stage (f32 -> bf16, reg path, same swizzled A layout)
  auto stageX = [&](int buf, int sx) {
    int row = tid >> 1, ch = tid & 1;
    const float* xr = x + ((size_t)vt * S_TOT + s0 + row) * F_IN + sx * 64 + ch * 32;
    f32x4 xv[8];
#pragma unroll
    for (int i = 0; i < 8; ++i) xv[i] = *(const f32x4*)(xr + i * 4);
#pragma unroll
    for (int i = 0; i < 4; ++i) {
      bf16x8 w;
#pragma unroll
      for (int jj = 0; jj < 4; ++jj) {
        w[jj] = (bf16_t)xv[2 * i][jj];
        w[4 + jj] = (bf16_t)xv[2 * i + 1][jj];
      }
      int seg = ch * 4 + i;
      *(bf16x8*)(&ab[buf][row * 64 + ((seg ^ (row & 7)) << 3)]) = w;
    }
  };

  f32x4 acc[4][4] = {};
  auto compute = [&](int buf) {
#pragma unroll
    for (int kcl = 0; kcl < 2; ++kcl) {
      bf16x8 bfr[4];
#pragma unroll
      for (int ni = 0; ni < 4; ++ni)
        bfr[ni] = *(const bf16x8*)(&bb[buf][(kcl * 8 + nw * 4 + ni) * 512 + l * 8]);
      bf16x8 afr[4];
      int seg = kcl * 4 + hi;
#pragma unroll
      for (int mi = 0; mi < 4; ++mi) {
        int rr = mw * 64 + mi * 16 + lo;
        afr[mi] = *(const bf16x8*)(&ab[buf][rr * 64 + ((seg ^ (rr & 7)) << 3)]);
      }
#pragma unroll
      for (int mi = 0; mi < 4; ++mi)
#pragma unroll
        for (int ni = 0; ni < 4; ++ni)
          acc[mi][ni] = __builtin_amdgcn_mfma_f32_16x16x32_bf16(afr[mi], bfr[ni], acc[mi][ni], 0, 0, 0);
    }
  };

  stageA(0, 0);
  stageB(0, Wp, 0);
  __syncthreads();

  for (int s = 0; s < NSUB; ++s) {
    int buf = s & 1;
    int s1 = s + 1;
    if (s1 < NMAIN) {
      stageA(buf ^ 1, s1);
      stageB(buf ^ 1, Wp, (s1 / TPK) * (RE / 32) + (s1 % TPK) * 2);
    } else if (XSK && s1 < NSUB) {
      int sx = s1 - NMAIN;
      stageX(buf ^ 1, sx);
      stageB(buf ^ 1, Wsp, sx * 2);
    }
    compute(buf);
    __syncthreads();
  }

  if (!XSK) {
    bf16_t* ob = outb + ((size_t)vt * S_TOT + s0) * 256;
#pragma unroll
    for (int ni = 0; ni < 4; ++ni) {
      int o = nsp * 128 + nw * 64 + ni * 16 + lo;
      float bv = bias[o];
      float s_ = 0.f, q_ = 0.f;
#pragma unroll
      for (int mi = 0; mi < 4; ++mi)
#pragma unroll
        for (int r2 = 0; r2 < 4; ++r2) {
          int srow = mw * 64 + mi * 16 + hi * 4 + r2;
          float v = acc[mi][ni][r2] + bv;
          ob[(size_t)srow * 256 + o] = (bf16_t)v;
          s_ += v; q_ += v * v;
        }
      s_ += __shfl_xor(s_, 16); s_ += __shfl_xor(s_, 32);
      q_ += __shfl_xor(q_, 16); q_ += __shfl_xor(q_, 32);
      if (hi == 0) {
        atomicAdd(&sum_c[vt * 256 + o], s_);
        atomicAdd(&ss_c[vt * 256 + o], q_);
      }
    }
  } else {
    float* of = outf + ((size_t)vt * S_TOT + s0) * 256;
#pragma unroll
    for (int ni = 0; ni < 4; ++ni) {
      int o = nsp * 128 + nw * 64 + ni * 16 + lo;
      float bv = bias[o] + biask[o];
#pragma unroll
      for (int mi = 0; mi < 4; ++mi)
#pragma unroll
        for (int r2 = 0; r2 < 4; ++r2) {
          int srow = mw * 64 + mi * 16 + hi * 4 + r2;
          of[(size_t)srow * 256 + o] = acc[mi][ni][r2] + bv;
        }
    }
  }
}

extern "C" void kernel_launch(void* const* d_in, const int* in_sizes, int n_in,
                              void* d_out, int out_size, void* d_ws, size_t ws_size,
                              hipStream_t stream) {
  const float* x      = (const float*)d_in[0];
  const int*   adjc   = (const int*)d_in[1];
  const float* gn1_s  = (const float*)d_in[2];
  const float* gn1_b  = (const float*)d_in[3];
  const float* gn2_s  = (const float*)d_in[4];
  const float* gn2_b  = (const float*)d_in[5];
  const float* W_skip = (const float*)d_in[6];
  const float* b_skip = (const float*)d_in[7];
  const float* W1     = (const float*)d_in[8];
  const float* b1     = (const float*)d_in[9];
  const float* W2     = (const float*)d_in[10];
  const float* b2     = (const float*)d_in[11];
  float* out = (float*)d_out;

  float* sum1  = (float*)d_ws;           // 128
  float* ss1   = sum1 + 128;             // 128
  float* sum_c = ss1 + 128;              // 1024
  float* ss_c  = sum_c + 1024;           // 1024
  float* a1    = ss_c + 1024;            // 512
  float* b1a   = a1 + 512;               // 512
  float* a2    = b1a + 512;              // 1024
  float* b2a   = a2 + 1024;              // 1024
  bf16_t* W1p  = (bf16_t*)(b2a + 1024);  // 294912
  bf16_t* W2p  = W1p + 294912;           // 589824
  bf16_t* Wsp  = W2p + 589824;           // 32768
  bf16_t* h1   = Wsp + 32768;            // 6291456
  bf16_t* out1 = h1 + 6291456;           // 12582912 (reused in place as h2)

  hipMemsetAsync(sum1, 0, (128 + 128 + 1024 + 1024) * sizeof(float), stream);
  pack_weights<<<448, 256, 0, stream>>>(W1, W2, W_skip, W1p, W2p, Wsp);
  gn1_stats<<<dim3(48, 4), 256, 0, stream>>>(x, sum1, ss1);
  fin_gn1<<<1, 512, 0, stream>>>(sum1, ss1, gn1_s, gn1_b, a1, b1a);
  apply_gn1<<<3072, 256, 0, stream>>>(x, a1, b1a, h1);
  conv_kernel<128, 18, false><<<768, 256, 0, stream>>>(
      h1, W1p, nullptr, nullptr, adjc, b1, nullptr, out1, nullptr, sum_c, ss_c);
  fin_gn2<<<1, 1024, 0, stream>>>(sum_c, ss_c, gn2_s, gn2_b, a2, b2a);
  apply_gn2<<<6144, 256, 0, stream>>>(out1, a2, b2a);
  conv_kernel<256, 38, true><<<768, 256, 0, stream>>>(
      out1, W2p, Wsp, x, adjc, b2, b_skip, nullptr, out, nullptr, nullptr);
}

// Round 4
// 154.054 us; speedup vs baseline: 1.3119x; 1.2338x over previous
//
#include <hip/hip_runtime.h>
#include <hip/hip_bf16.h>

typedef __bf16 bf16_t;
typedef __bf16 bf16x8 __attribute__((ext_vector_type(8)));
typedef float f32x4 __attribute__((ext_vector_type(4)));

#define S_TOT 12288
#define F_IN 128
#define F_OUT 256
#define EPS 1e-5f

static __device__ __forceinline__ float silu_f(float v) {
  return v / (1.0f + __expf(-v));
}

static __device__ __forceinline__ void gll16(const bf16_t* g, bf16_t* l) {
  __builtin_amdgcn_global_load_lds(
      (const __attribute__((address_space(1))) void*)(const void*)g,
      (__attribute__((address_space(3))) void*)(void*)l, 16, 0, 0);
}

// ---------------- pack weights into MFMA B-frag order ----------------
// Unit = (kc_global, cb): lane l holds B[f=32*kc+8*(l>>4)+j][o=16cb+(l&15)]
// stored at unit*1024B + l*16B. W1: 36*16=576 units; W2: 72*16=1152; Wsk: 4*16=64.
__global__ void pack_weights(const float* __restrict__ W1,
                             const float* __restrict__ W2,
                             const float* __restrict__ Wsk,
                             bf16_t* __restrict__ W1p,
                             bf16_t* __restrict__ W2p,
                             bf16_t* __restrict__ Wsp) {
  int w = blockIdx.x * 4 + (threadIdx.x >> 6);
  int l = threadIdx.x & 63;
  int lo = l & 15, hi = l >> 4;
  const float* src;
  bf16_t* dst;
  int fbase, obase;
  if (w < 576) {
    int k = w >> 6, rem = w & 63, kc = rem >> 4, cb = rem & 15;
    src = W1 + k * 32768;
    dst = W1p + (size_t)w * 512;
    fbase = 32 * kc + 8 * hi; obase = 16 * cb + lo;
  } else if (w < 1728) {
    int idx = w - 576;
    int k = idx >> 7, rem = idx & 127, kc = rem >> 4, cb = rem & 15;
    src = W2 + k * 65536;
    dst = W2p + (size_t)idx * 512;
    fbase = 32 * kc + 8 * hi; obase = 16 * cb + lo;
  } else {
    int idx = w - 1728;
    int kc = idx >> 4, cb = idx & 15;
    src = Wsk;
    dst = Wsp + (size_t)idx * 512;
    fbase = 32 * kc + 8 * hi; obase = 16 * cb + lo;
  }
  bf16x8 v;
#pragma unroll
  for (int j = 0; j < 8; ++j)
    v[j] = (bf16_t)src[(fbase + j) * 256 + obase];
  *(bf16x8*)(dst + l * 8) = v;
}

// ---------------- GN1 stats ----------------
__global__ void gn1_stats(const float* __restrict__ x,
                          float* __restrict__ sum1, float* __restrict__ ss1) {
  int vt = blockIdx.y;
  int s0 = blockIdx.x * 256;
  int t = threadIdx.x;
  int col = t & 31, ro = t >> 5;
  float s_ = 0.f, q_ = 0.f;
  const f32x4* xp = (const f32x4*)(x + ((size_t)vt * S_TOT + s0) * F_IN);
#pragma unroll 4
  for (int it = 0; it < 32; ++it) {
    f32x4 v = xp[(size_t)(it * 8 + ro) * 32 + col];
    s_ += v[0] + v[1] + v[2] + v[3];
    q_ += v[0]*v[0] + v[1]*v[1] + v[2]*v[2] + v[3]*v[3];
  }
  __shared__ float gs[32], gq[32];
  if (t < 32) { gs[t] = 0.f; gq[t] = 0.f; }
  __syncthreads();
  atomicAdd(&gs[col], s_);
  atomicAdd(&gq[col], q_);
  __syncthreads();
  if (t < 32) {
    atomicAdd(&sum1[vt * 32 + t], gs[t]);
    atomicAdd(&ss1[vt * 32 + t], gq[t]);
  }
}

// ---------------- apply GN1 (affine computed inline) + SiLU -> h1 ----------------
__global__ void apply_gn1(const float* __restrict__ x,
                          const float* __restrict__ sum1, const float* __restrict__ ss1,
                          const float* __restrict__ gs, const float* __restrict__ gb,
                          bf16_t* __restrict__ h1) {
  size_t base = ((size_t)blockIdx.x * 256 + threadIdx.x) * 8;
  int vt = (int)(base / ((size_t)S_TOT * F_IN));
  int c0 = (int)(base & (F_IN - 1));
  const f32x4* xp = (const f32x4*)(x + base);
  f32x4 v0 = xp[0], v1 = xp[1];
  float N = (float)(S_TOT * 4);
  bf16x8 o;
#pragma unroll
  for (int gi = 0; gi < 2; ++gi) {
    int g = (c0 >> 2) + gi;
    float mean = sum1[vt * 32 + g] / N;
    float var = ss1[vt * 32 + g] / N - mean * mean;
    float r = rsqrtf(var + EPS);
    f32x4 v = gi ? v1 : v0;
#pragma unroll
    for (int j = 0; j < 4; ++j) {
      int c = g * 4 + j;
      float a = r * gs[c];
      float b = gb[c] - mean * a;
      o[gi * 4 + j] = (bf16_t)silu_f(v[j] * a + b);
    }
  }
  *(bf16x8*)(h1 + base) = o;
}

// ---------------- apply GN2 (affine inline, 8-ch groups) + SiLU in place ----------------
__global__ void apply_gn2(bf16_t* __restrict__ h,
                          const float* __restrict__ sum_c, const float* __restrict__ ss_c,
                          const float* __restrict__ gs, const float* __restrict__ gb) {
  size_t base = ((size_t)blockIdx.x * 256 + threadIdx.x) * 8;
  int vt = (int)(base / ((size_t)S_TOT * F_OUT));
  int c0 = (int)(base & (F_OUT - 1));
  int g = c0 >> 3;                        // 8 channels = exactly one group
  bf16x8 v = *(const bf16x8*)(h + base);
  float sg = 0.f, qg = 0.f;
#pragma unroll
  for (int j = 0; j < 8; ++j) {
    sg += sum_c[vt * 256 + g * 8 + j];
    qg += ss_c[vt * 256 + g * 8 + j];
  }
  float N = (float)(S_TOT * 8);
  float mean = sg / N;
  float var = qg / N - mean * mean;
  float r = rsqrtf(var + EPS);
  bf16x8 o;
#pragma unroll
  for (int j = 0; j < 8; ++j) {
    int c = g * 8 + j;
    float a = r * gs[c];
    float b = gb[c] - mean * a;
    o[j] = (bf16_t)silu_f((float)v[j] * a + b);
  }
  *(bf16x8*)(h + base) = o;
}

// ---------------- unified gather-conv GEMM v4 ----------------
// Block tile 128 rows x 128 cols (nsp half), 256 threads = 4 waves of 64x64.
// K-step 32, double-buffered; LDS = 4.6K adj + 2*(8K A + 8K B) = 36.6KB -> 4 blocks/CU.
// A gathered via global_load_lds, source pre-swizzled seg^( (row>>1)&3 ) for 64B rows.
// RE = source row elements. XSK: 4 extra x-skip K32 steps (f32 -> bf16 reg path).
template<int RE, int NSUB, bool XSK>
__global__ __launch_bounds__(256, 4) void conv_kernel(
    const bf16_t* __restrict__ hsrc, const bf16_t* __restrict__ Wp,
    const bf16_t* __restrict__ Wsp, const float* __restrict__ x,
    const int* __restrict__ adjc, const float* __restrict__ bias,
    const float* __restrict__ biask, bf16_t* __restrict__ outb,
    float* __restrict__ outf, float* __restrict__ sum_c, float* __restrict__ ss_c) {
  const int tid = threadIdx.x;
  const int wv = tid >> 6, l = tid & 63;
  const int lo = l & 15, hi = l >> 4;
  const int mw = wv >> 1, nw = wv & 1;

  int swz = ((blockIdx.x & 7) * 96) + (blockIdx.x >> 3);   // bijective: 768 = 8*96
  int vt = swz / 192;
  int rem = swz - vt * 192;
  int sblk = rem >> 1, nsp = rem & 1;
  int s0 = sblk * 128;

  __shared__ int adjs[1152];
  __shared__ bf16_t ab[2][4096];   // 128 rows x 32 (64B rows), seg-XOR swizzled
  __shared__ bf16_t bb[2][4096];   // 8 frag-units x 512

  for (int i = tid; i < 1152; i += 256) adjs[i] = adjc[s0 * 9 + i];
  __syncthreads();

  const bf16_t* hb = hsrc + (size_t)vt * ((size_t)S_TOT * RE);
  constexpr int TPK = RE / 32;            // K32-steps per tap
  constexpr int NMAIN = XSK ? (NSUB - 4) : NSUB;

  // A-stage: 8 gll16 (2/wave); instr j covers rows 16j..16j+15 (64B each).
  auto stageA = [&](int buf, int s) {
    int tap = s / TPK, chunk = s % TPK;
#pragma unroll
    for (int j2 = 0; j2 < 2; ++j2) {
      int j = wv * 2 + j2;
      int row = j * 16 + (l >> 2);
      int segs = (l & 3) ^ ((row >> 1) & 3);
      int arow = adjs[row * 9 + tap];
      const bf16_t* g = hb + (size_t)arow * RE + chunk * 32 + segs * 8;
      gll16(g, &ab[buf][j * 512]);
    }
  };
  // B-stage: 8 gll16 (2/wave); unit = cb-local, frag-linear (no swizzle needed).
  auto stageB = [&](int buf, const bf16_t* wsrc, int kcg) {
#pragma unroll
    for (int j2 = 0; j2 < 2; ++j2) {
      int ul = wv * 2 + j2;
      const bf16_t* g = wsrc + ((size_t)(kcg * 16 + nsp * 8 + ul)) * 512 + l * 8;
      gll16(g, &bb[buf][ul * 512]);
    }
  };
  // x-skip stage (f32 -> bf16 reg path, same swizzled A layout)
  auto stageX = [&](int buf, int sx) {
    int row = tid >> 1, h = tid & 1;
    const float* xr = x + ((size_t)vt * S_TOT + s0 + row) * F_IN + sx * 32 + h * 16;
    f32x4 xv[4];
#pragma unroll
    for (int i = 0; i < 4; ++i) xv[i] = *(const f32x4*)(xr + i * 4);
#pragma unroll
    for (int i = 0; i < 2; ++i) {
      bf16x8 w;
#pragma unroll
      for (int jj = 0; jj < 4; ++jj) {
        w[jj] = (bf16_t)xv[2 * i][jj];
        w[4 + jj] = (bf16_t)xv[2 * i + 1][jj];
      }
      int seg = 2 * h + i;
      *(bf16x8*)(&ab[buf][row * 32 + (((seg ^ ((row >> 1) & 3))) << 3)]) = w;
    }
  };

  f32x4 acc[4][4] = {};
  auto compute = [&](int buf) {
    bf16x8 bfr[4];
#pragma unroll
    for (int ni = 0; ni < 4; ++ni)
      bfr[ni] = *(const bf16x8*)(&bb[buf][(nw * 4 + ni) * 512 + l * 8]);
    bf16x8 afr[4];
#pragma unroll
    for (int mi = 0; mi < 4; ++mi) {
      int rr = mw * 64 + mi * 16 + lo;
      afr[mi] = *(const bf16x8*)(&ab[buf][rr * 32 + ((hi ^ ((rr >> 1) & 3)) << 3)]);
    }
#pragma unroll
    for (int mi = 0; mi < 4; ++mi)
#pragma unroll
      for (int ni = 0; ni < 4; ++ni)
        acc[mi][ni] = __builtin_amdgcn_mfma_f32_16x16x32_bf16(afr[mi], bfr[ni], acc[mi][ni], 0, 0, 0);
  };

  stageA(0, 0);
  stageB(0, Wp, 0);
  __syncthreads();

  for (int s = 0; s < NSUB; ++s) {
    int buf = s & 1;
    int s1 = s + 1;
    if (s1 < NMAIN) {
      stageA(buf ^ 1, s1);
      stageB(buf ^ 1, Wp, s1);
    } else if (XSK && s1 < NSUB) {
      int sx = s1 - NMAIN;
      stageX(buf ^ 1, sx);
      stageB(buf ^ 1, Wsp, sx);
    }
    compute(buf);
    __syncthreads();
  }

  if (!XSK) {
    bf16_t* ob = outb + ((size_t)vt * S_TOT + s0) * 256;
#pragma unroll
    for (int ni = 0; ni < 4; ++ni) {
      int o = nsp * 128 + nw * 64 + ni * 16 + lo;
      float bv = bias[o];
      float s_ = 0.f, q_ = 0.f;
#pragma unroll
      for (int mi = 0; mi < 4; ++mi)
#pragma unroll
        for (int r2 = 0; r2 < 4; ++r2) {
          int srow = mw * 64 + mi * 16 + hi * 4 + r2;
          float v = acc[mi][ni][r2] + bv;
          ob[(size_t)srow * 256 + o] = (bf16_t)v;
          s_ += v; q_ += v * v;
        }
      s_ += __shfl_xor(s_, 16); s_ += __shfl_xor(s_, 32);
      q_ += __shfl_xor(q_, 16); q_ += __shfl_xor(q_, 32);
      if (hi == 0) {
        atomicAdd(&sum_c[vt * 256 + o], s_);
        atomicAdd(&ss_c[vt * 256 + o], q_);
      }
    }
  } else {
    float* of = outf + ((size_t)vt * S_TOT + s0) * 256;
#pragma unroll
    for (int ni = 0; ni < 4; ++ni) {
      int o = nsp * 128 + nw * 64 + ni * 16 + lo;
      float bv = bias[o] + biask[o];
#pragma unroll
      for (int mi = 0; mi < 4; ++mi)
#pragma unroll
        for (int r2 = 0; r2 < 4; ++r2) {
          int srow = mw * 64 + mi * 16 + hi * 4 + r2;
          of[(size_t)srow * 256 + o] = acc[mi][ni][r2] + bv;
        }
    }
  }
}

extern "C" void kernel_launch(void* const* d_in, const int* in_sizes, int n_in,
                              void* d_out, int out_size, void* d_ws, size_t ws_size,
                              hipStream_t stream) {
  const float* x      = (const float*)d_in[0];
  const int*   adjc   = (const int*)d_in[1];
  const float* gn1_s  = (const float*)d_in[2];
  const float* gn1_b  = (const float*)d_in[3];
  const float* gn2_s  = (const float*)d_in[4];
  const float* gn2_b  = (const float*)d_in[5];
  const float* W_skip = (const float*)d_in[6];
  const float* b_skip = (const float*)d_in[7];
  const float* W1     = (const float*)d_in[8];
  const float* b1     = (const float*)d_in[9];
  const float* W2     = (const float*)d_in[10];
  const float* b2     = (const float*)d_in[11];
  float* out = (float*)d_out;

  float* sum1  = (float*)d_ws;           // 128
  float* ss1   = sum1 + 128;             // 128
  float* sum_c = ss1 + 128;              // 1024
  float* ss_c  = sum_c + 1024;           // 1024
  float* a1    = ss_c + 1024;            // 512 (unused, kept for layout)
  float* b1a   = a1 + 512;               // 512 (unused)
  float* a2    = b1a + 512;              // 1024 (unused)
  float* b2a   = a2 + 1024;              // 1024 (unused)
  bf16_t* W1p  = (bf16_t*)(b2a + 1024);  // 294912
  bf16_t* W2p  = W1p + 294912;           // 589824
  bf16_t* Wsp  = W2p + 589824;           // 32768
  bf16_t* h1   = Wsp + 32768;            // 6291456
  bf16_t* out1 = h1 + 6291456;           // 12582912 (reused in place as h2)

  hipMemsetAsync(sum1, 0, (128 + 128 + 1024 + 1024) * sizeof(float), stream);
  pack_weights<<<448, 256, 0, stream>>>(W1, W2, W_skip, W1p, W2p, Wsp);
  gn1_stats<<<dim3(48, 4), 256, 0, stream>>>(x, sum1, ss1);
  apply_gn1<<<3072, 256, 0, stream>>>(x, sum1, ss1, gn1_s, gn1_b, h1);
  conv_kernel<128, 36, false><<<768, 256, 0, stream>>>(
      h1, W1p, nullptr, nullptr, adjc, b1, nullptr, out1, nullptr, sum_c, ss_c);
  apply_gn2<<<6144, 256, 0, stream>>>(out1, sum_c, ss_c, gn2_s, gn2_b);
  conv_kernel<256, 76, true><<<768, 256, 0, stream>>>(
      out1, W2p, Wsp, x, adjc, b2, b_skip, nullptr, out, nullptr, nullptr);
}

// Round 5
// 153.180 us; speedup vs baseline: 1.3194x; 1.0057x over previous
//
#include <hip/hip_runtime.h>
#include <hip/hip_bf16.h>

typedef __bf16 bf16_t;
typedef __bf16 bf16x8 __attribute__((ext_vector_type(8)));
typedef float f32x4 __attribute__((ext_vector_type(4)));

#define S_TOT 12288
#define F_IN 128
#define F_OUT 256
#define EPS 1e-5f

static __device__ __forceinline__ float silu_f(float v) {
  return v / (1.0f + __expf(-v));
}

static __device__ __forceinline__ void gll16(const bf16_t* g, bf16_t* l) {
  __builtin_amdgcn_global_load_lds(
      (const __attribute__((address_space(1))) void*)(const void*)g,
      (__attribute__((address_space(3))) void*)(void*)l, 16, 0, 0);
}

// ---------------- pack weights into MFMA B-frag order ----------------
// Unit = (kc_global, cb): lane l holds B[f=32*kc+8*(l>>4)+j][o=16cb+(l&15)]
// stored at unit*1024B + l*16B. W1: 36*16=576 units; W2: 72*16=1152; Wsk: 4*16=64.
__global__ void pack_weights(const float* __restrict__ W1,
                             const float* __restrict__ W2,
                             const float* __restrict__ Wsk,
                             bf16_t* __restrict__ W1p,
                             bf16_t* __restrict__ W2p,
                             bf16_t* __restrict__ Wsp) {
  int w = blockIdx.x * 4 + (threadIdx.x >> 6);
  int l = threadIdx.x & 63;
  int lo = l & 15, hi = l >> 4;
  const float* src;
  bf16_t* dst;
  int fbase, obase;
  if (w < 576) {
    int k = w >> 6, rem = w & 63, kc = rem >> 4, cb = rem & 15;
    src = W1 + k * 32768;
    dst = W1p + (size_t)w * 512;
    fbase = 32 * kc + 8 * hi; obase = 16 * cb + lo;
  } else if (w < 1728) {
    int idx = w - 576;
    int k = idx >> 7, rem = idx & 127, kc = rem >> 4, cb = rem & 15;
    src = W2 + k * 65536;
    dst = W2p + (size_t)idx * 512;
    fbase = 32 * kc + 8 * hi; obase = 16 * cb + lo;
  } else {
    int idx = w - 1728;
    int kc = idx >> 4, cb = idx & 15;
    src = Wsk;
    dst = Wsp + (size_t)idx * 512;
    fbase = 32 * kc + 8 * hi; obase = 16 * cb + lo;
  }
  bf16x8 v;
#pragma unroll
  for (int j = 0; j < 8; ++j)
    v[j] = (bf16_t)src[(fbase + j) * 256 + obase];
  *(bf16x8*)(dst + l * 8) = v;
}

// ---------------- GN1 stats ----------------
__global__ void gn1_stats(const float* __restrict__ x,
                          float* __restrict__ sum1, float* __restrict__ ss1) {
  int vt = blockIdx.y;
  int s0 = blockIdx.x * 256;
  int t = threadIdx.x;
  int col = t & 31, ro = t >> 5;
  float s_ = 0.f, q_ = 0.f;
  const f32x4* xp = (const f32x4*)(x + ((size_t)vt * S_TOT + s0) * F_IN);
#pragma unroll 4
  for (int it = 0; it < 32; ++it) {
    f32x4 v = xp[(size_t)(it * 8 + ro) * 32 + col];
    s_ += v[0] + v[1] + v[2] + v[3];
    q_ += v[0]*v[0] + v[1]*v[1] + v[2]*v[2] + v[3]*v[3];
  }
  __shared__ float gs[32], gq[32];
  if (t < 32) { gs[t] = 0.f; gq[t] = 0.f; }
  __syncthreads();
  atomicAdd(&gs[col], s_);
  atomicAdd(&gq[col], q_);
  __syncthreads();
  if (t < 32) {
    atomicAdd(&sum1[vt * 32 + t], gs[t]);
    atomicAdd(&ss1[vt * 32 + t], gq[t]);
  }
}

// ---------------- apply GN1 (affine computed inline) + SiLU -> h1 ----------------
__global__ void apply_gn1(const float* __restrict__ x,
                          const float* __restrict__ sum1, const float* __restrict__ ss1,
                          const float* __restrict__ gs, const float* __restrict__ gb,
                          bf16_t* __restrict__ h1) {
  size_t base = ((size_t)blockIdx.x * 256 + threadIdx.x) * 8;
  int vt = (int)(base / ((size_t)S_TOT * F_IN));
  int c0 = (int)(base & (F_IN - 1));
  const f32x4* xp = (const f32x4*)(x + base);
  f32x4 v0 = xp[0], v1 = xp[1];
  float N = (float)(S_TOT * 4);
  bf16x8 o;
#pragma unroll
  for (int gi = 0; gi < 2; ++gi) {
    int g = (c0 >> 2) + gi;
    float mean = sum1[vt * 32 + g] / N;
    float var = ss1[vt * 32 + g] / N - mean * mean;
    float r = rsqrtf(var + EPS);
    f32x4 v = gi ? v1 : v0;
#pragma unroll
    for (int j = 0; j < 4; ++j) {
      int c = g * 4 + j;
      float a = r * gs[c];
      float b = gb[c] - mean * a;
      o[gi * 4 + j] = (bf16_t)silu_f(v[j] * a + b);
    }
  }
  *(bf16x8*)(h1 + base) = o;
}

// ---------------- apply GN2 (affine inline, 8-ch groups) + SiLU in place ----------------
__global__ void apply_gn2(bf16_t* __restrict__ h,
                          const float* __restrict__ sum_c, const float* __restrict__ ss_c,
                          const float* __restrict__ gs, const float* __restrict__ gb) {
  size_t base = ((size_t)blockIdx.x * 256 + threadIdx.x) * 8;
  int vt = (int)(base / ((size_t)S_TOT * F_OUT));
  int c0 = (int)(base & (F_OUT - 1));
  int g = c0 >> 3;                        // 8 channels = exactly one group
  bf16x8 v = *(const bf16x8*)(h + base);
  float sg = 0.f, qg = 0.f;
#pragma unroll
  for (int j = 0; j < 8; ++j) {
    sg += sum_c[vt * 256 + g * 8 + j];
    qg += ss_c[vt * 256 + g * 8 + j];
  }
  float N = (float)(S_TOT * 8);
  float mean = sg / N;
  float var = qg / N - mean * mean;
  float r = rsqrtf(var + EPS);
  bf16x8 o;
#pragma unroll
  for (int j = 0; j < 8; ++j) {
    int c = g * 8 + j;
    float a = r * gs[c];
    float b = gb[c] - mean * a;
    o[j] = (bf16_t)silu_f((float)v[j] * a + b);
  }
  *(bf16x8*)(h + base) = o;
}

// ---------------- unified gather-conv GEMM v5 ----------------
// Block tile 128 rows x 128 cols (nsp half), 256 threads = 4 waves of 64x64.
// K-step 32, RING-3 buffered with counted vmcnt across raw s_barrier:
// loads stay in flight for 2 full substages (covers ~900cy HBM gather misses).
// LDS = 4.6K adj + 3*(8K A + 8K B) = 52.5KB -> 3 blocks/CU (768 blocks = exact fit).
// Per-iteration: vmcnt(4) [stage(s) landed] -> s_barrier -> issue stage(s+2) -> MFMA.
template<int RE, int NSUB, bool XSK>
__global__ __launch_bounds__(256, 3) void conv_kernel(
    const bf16_t* __restrict__ hsrc, const bf16_t* __restrict__ Wp,
    const bf16_t* __restrict__ Wsp, const float* __restrict__ x,
    const int* __restrict__ adjc, const float* __restrict__ bias,
    const float* __restrict__ biask, bf16_t* __restrict__ outb,
    float* __restrict__ outf, float* __restrict__ sum_c, float* __restrict__ ss_c) {
  const int tid = threadIdx.x;
  const int wv = tid >> 6, l = tid & 63;
  const int lo = l & 15, hi = l >> 4;
  const int mw = wv >> 1, nw = wv & 1;

  int swz = ((blockIdx.x & 7) * 96) + (blockIdx.x >> 3);   // bijective: 768 = 8*96
  int vt = swz / 192;
  int rem = swz - vt * 192;
  int sblk = rem >> 1, nsp = rem & 1;
  int s0 = sblk * 128;

  __shared__ int adjs[1152];
  __shared__ bf16_t ab[3][4096];   // 128 rows x 32 (64B rows), seg-XOR swizzled
  __shared__ bf16_t bb[3][4096];   // 8 frag-units x 512

  for (int i = tid; i < 1152; i += 256) adjs[i] = adjc[s0 * 9 + i];
  __syncthreads();

  const bf16_t* hb = hsrc + (size_t)vt * ((size_t)S_TOT * RE);
  constexpr int TPK = RE / 32;            // K32-steps per tap
  constexpr int NMAIN = XSK ? (NSUB - 4) : NSUB;

  // A-stage: 2 gll16 per wave; instr j covers rows 16j..16j+15 (64B each).
  auto stageA = [&](int buf, int s) {
    int tap = s / TPK, chunk = s % TPK;
#pragma unroll
    for (int j2 = 0; j2 < 2; ++j2) {
      int j = wv * 2 + j2;
      int row = j * 16 + (l >> 2);
      int segs = (l & 3) ^ ((row >> 1) & 3);
      int arow = adjs[row * 9 + tap];
      const bf16_t* g = hb + (size_t)arow * RE + chunk * 32 + segs * 8;
      gll16(g, &ab[buf][j * 512]);
    }
  };
  // B-stage: 2 gll16 per wave; unit = cb-local, frag-linear (no swizzle needed).
  auto stageB = [&](int buf, const bf16_t* wsrc, int kcg) {
#pragma unroll
    for (int j2 = 0; j2 < 2; ++j2) {
      int ul = wv * 2 + j2;
      const bf16_t* g = wsrc + ((size_t)(kcg * 16 + nsp * 8 + ul)) * 512 + l * 8;
      gll16(g, &bb[buf][ul * 512]);
    }
  };
  // x-skip stage (f32 -> bf16 reg path, same swizzled A layout)
  auto stageX = [&](int buf, int sx) {
    int row = tid >> 1, h = tid & 1;
    const float* xr = x + ((size_t)vt * S_TOT + s0 + row) * F_IN + sx * 32 + h * 16;
    f32x4 xv[4];
#pragma unroll
    for (int i = 0; i < 4; ++i) xv[i] = *(const f32x4*)(xr + i * 4);
#pragma unroll
    for (int i = 0; i < 2; ++i) {
      bf16x8 w;
#pragma unroll
      for (int jj = 0; jj < 4; ++jj) {
        w[jj] = (bf16_t)xv[2 * i][jj];
        w[4 + jj] = (bf16_t)xv[2 * i + 1][jj];
      }
      int seg = 2 * h + i;
      *(bf16x8*)(&ab[buf][row * 32 + (((seg ^ ((row >> 1) & 3))) << 3)]) = w;
    }
  };

  f32x4 acc[4][4] = {};
  auto compute = [&](int buf) {
    bf16x8 bfr[4];
#pragma unroll
    for (int ni = 0; ni < 4; ++ni)
      bfr[ni] = *(const bf16x8*)(&bb[buf][(nw * 4 + ni) * 512 + l * 8]);
    bf16x8 afr[4];
#pragma unroll
    for (int mi = 0; mi < 4; ++mi) {
      int rr = mw * 64 + mi * 16 + lo;
      afr[mi] = *(const bf16x8*)(&ab[buf][rr * 32 + ((hi ^ ((rr >> 1) & 3)) << 3)]);
    }
    __builtin_amdgcn_s_setprio(1);
#pragma unroll
    for (int mi = 0; mi < 4; ++mi)
#pragma unroll
      for (int ni = 0; ni < 4; ++ni)
        acc[mi][ni] = __builtin_amdgcn_mfma_f32_16x16x32_bf16(afr[mi], bfr[ni], acc[mi][ni], 0, 0, 0);
    __builtin_amdgcn_s_setprio(0);
  };

  // ---- ring-3 pipelined main loop ----
  stageA(0, 0); stageB(0, Wp, 0);
  stageA(1, 1); stageB(1, Wp, 1);
  for (int s = 0; s < NMAIN; ++s) {
    // own stage(s) loads landed (only stage(s+1)'s 4 VMEM may remain in flight)
    if (s + 1 < NMAIN) asm volatile("s_waitcnt vmcnt(4)" ::: "memory");
    else               asm volatile("s_waitcnt vmcnt(0)" ::: "memory");
    __builtin_amdgcn_s_barrier();        // all waves: stage(s) visible, buf (s+2)%3 free
    __builtin_amdgcn_sched_barrier(0);   // no ds_read hoisting above the barrier
    int s2 = s + 2;
    if (s2 < NMAIN) {
      int nb = s2 % 3;
      stageA(nb, s2);
      stageB(nb, Wp, s2);
    }
    compute(s % 3);
  }

  // ---- x-skip tail (simple sync structure, 4 substages) ----
  if (XSK) {
    for (int sx = 0; sx < 4; ++sx) {
      int cur = (NMAIN + sx) % 3;
      __syncthreads();
      stageX(cur, sx);
      stageB(cur, Wsp, sx);
      __syncthreads();
      compute(cur);
    }
  }

  if (!XSK) {
    bf16_t* ob = outb + ((size_t)vt * S_TOT + s0) * 256;
#pragma unroll
    for (int ni = 0; ni < 4; ++ni) {
      int o = nsp * 128 + nw * 64 + ni * 16 + lo;
      float bv = bias[o];
      float s_ = 0.f, q_ = 0.f;
#pragma unroll
      for (int mi = 0; mi < 4; ++mi)
#pragma unroll
        for (int r2 = 0; r2 < 4; ++r2) {
          int srow = mw * 64 + mi * 16 + hi * 4 + r2;
          float v = acc[mi][ni][r2] + bv;
          ob[(size_t)srow * 256 + o] = (bf16_t)v;
          s_ += v; q_ += v * v;
        }
      s_ += __shfl_xor(s_, 16); s_ += __shfl_xor(s_, 32);
      q_ += __shfl_xor(q_, 16); q_ += __shfl_xor(q_, 32);
      if (hi == 0) {
        atomicAdd(&sum_c[vt * 256 + o], s_);
        atomicAdd(&ss_c[vt * 256 + o], q_);
      }
    }
  } else {
    float* of = outf + ((size_t)vt * S_TOT + s0) * 256;
#pragma unroll
    for (int ni = 0; ni < 4; ++ni) {
      int o = nsp * 128 + nw * 64 + ni * 16 + lo;
      float bv = bias[o] + biask[o];
#pragma unroll
      for (int mi = 0; mi < 4; ++mi)
#pragma unroll
        for (int r2 = 0; r2 < 4; ++r2) {
          int srow = mw * 64 + mi * 16 + hi * 4 + r2;
          of[(size_t)srow * 256 + o] = acc[mi][ni][r2] + bv;
        }
    }
  }
}

extern "C" void kernel_launch(void* const* d_in, const int* in_sizes, int n_in,
                              void* d_out, int out_size, void* d_ws, size_t ws_size,
                              hipStream_t stream) {
  const float* x      = (const float*)d_in[0];
  const int*   adjc   = (const int*)d_in[1];
  const float* gn1_s  = (const float*)d_in[2];
  const float* gn1_b  = (const float*)d_in[3];
  const float* gn2_s  = (const float*)d_in[4];
  const float* gn2_b  = (const float*)d_in[5];
  const float* W_skip = (const float*)d_in[6];
  const float* b_skip = (const float*)d_in[7];
  const float* W1     = (const float*)d_in[8];
  const float* b1     = (const float*)d_in[9];
  const float* W2     = (const float*)d_in[10];
  const float* b2     = (const float*)d_in[11];
  float* out = (float*)d_out;

  float* sum1  = (float*)d_ws;           // 128
  float* ss1   = sum1 + 128;             // 128
  float* sum_c = ss1 + 128;              // 1024
  float* ss_c  = sum_c + 1024;           // 1024
  float* pad   = ss_c + 1024;            // 3072 (layout pad)
  bf16_t* W1p  = (bf16_t*)(pad + 3072);  // 294912
  bf16_t* W2p  = W1p + 294912;           // 589824
  bf16_t* Wsp  = W2p + 589824;           // 32768
  bf16_t* h1   = Wsp + 32768;            // 6291456
  bf16_t* out1 = h1 + 6291456;           // 12582912 (reused in place as h2)

  hipMemsetAsync(sum1, 0, (128 + 128 + 1024 + 1024) * sizeof(float), stream);
  pack_weights<<<448, 256, 0, stream>>>(W1, W2, W_skip, W1p, W2p, Wsp);
  gn1_stats<<<dim3(48, 4), 256, 0, stream>>>(x, sum1, ss1);
  apply_gn1<<<3072, 256, 0, stream>>>(x, sum1, ss1, gn1_s, gn1_b, h1);
  conv_kernel<128, 36, false><<<768, 256, 0, stream>>>(
      h1, W1p, nullptr, nullptr, adjc, b1, nullptr, out1, nullptr, sum_c, ss_c);
  apply_gn2<<<6144, 256, 0, stream>>>(out1, sum_c, ss_c, gn2_s, gn2_b);
  conv_kernel<256, 76, true><<<768, 256, 0, stream>>>(
      out1, W2p, Wsp, x, adjc, b2, b_skip, nullptr, out, nullptr, nullptr);
}

// Round 6
// 152.210 us; speedup vs baseline: 1.3278x; 1.0064x over previous
//
#include <hip/hip_runtime.h>
#include <hip/hip_bf16.h>

typedef __bf16 bf16_t;
typedef __bf16 bf16x8 __attribute__((ext_vector_type(8)));
typedef float f32x4 __attribute__((ext_vector_type(4)));
typedef int i32x4 __attribute__((ext_vector_type(4)));

#define S_TOT 12288
#define F_IN 128
#define F_OUT 256
#define EPS 1e-5f

static __device__ __forceinline__ float silu_f(float v) {
  return v / (1.0f + __expf(-v));
}

static __device__ __forceinline__ void gll16(const bf16_t* g, bf16_t* l) {
  __builtin_amdgcn_global_load_lds(
      (const __attribute__((address_space(1))) void*)(const void*)g,
      (__attribute__((address_space(3))) void*)(void*)l, 16, 0, 0);
}

// ---------------- prep: pack weights (blocks 0..447) + GN1 stats (448..639) ----
// Pack unit = (kc_global, cb): lane l holds B[f=32*kc+8*(l>>4)+j][o=16cb+(l&15)]
// at unit*1024B + l*16B. W1: 576 units; W2: 1152; Wsk: 64.
__global__ void prep_kernel(const float* __restrict__ W1,
                            const float* __restrict__ W2,
                            const float* __restrict__ Wsk,
                            bf16_t* __restrict__ W1p,
                            bf16_t* __restrict__ W2p,
                            bf16_t* __restrict__ Wsp,
                            const float* __restrict__ x,
                            float* __restrict__ sum1, float* __restrict__ ss1) {
  __shared__ float gs[32], gq[32];
  if (blockIdx.x < 448) {
    int w = blockIdx.x * 4 + (threadIdx.x >> 6);
    int l = threadIdx.x & 63;
    int lo = l & 15, hi = l >> 4;
    const float* src;
    bf16_t* dst;
    int fbase, obase;
    if (w < 576) {
      int k = w >> 6, rem = w & 63, kc = rem >> 4, cb = rem & 15;
      src = W1 + k * 32768;
      dst = W1p + (size_t)w * 512;
      fbase = 32 * kc + 8 * hi; obase = 16 * cb + lo;
    } else if (w < 1728) {
      int idx = w - 576;
      int k = idx >> 7, rem = idx & 127, kc = rem >> 4, cb = rem & 15;
      src = W2 + k * 65536;
      dst = W2p + (size_t)idx * 512;
      fbase = 32 * kc + 8 * hi; obase = 16 * cb + lo;
    } else {
      int idx = w - 1728;
      int kc = idx >> 4, cb = idx & 15;
      src = Wsk;
      dst = Wsp + (size_t)idx * 512;
      fbase = 32 * kc + 8 * hi; obase = 16 * cb + lo;
    }
    bf16x8 v;
#pragma unroll
    for (int j = 0; j < 8; ++j)
      v[j] = (bf16_t)src[(fbase + j) * 256 + obase];
    *(bf16x8*)(dst + l * 8) = v;
  } else {
    int blk = blockIdx.x - 448;       // 192 blocks: vt = blk%4, sb = blk/4
    int vt = blk & 3;
    int s0 = (blk >> 2) * 256;
    int t = threadIdx.x;
    int col = t & 31, ro = t >> 5;
    float s_ = 0.f, q_ = 0.f;
    const f32x4* xp = (const f32x4*)(x + ((size_t)vt * S_TOT + s0) * F_IN);
#pragma unroll 4
    for (int it = 0; it < 32; ++it) {
      f32x4 v = xp[(size_t)(it * 8 + ro) * 32 + col];
      s_ += v[0] + v[1] + v[2] + v[3];
      q_ += v[0]*v[0] + v[1]*v[1] + v[2]*v[2] + v[3]*v[3];
    }
    if (t < 32) { gs[t] = 0.f; gq[t] = 0.f; }
    __syncthreads();
    atomicAdd(&gs[col], s_);
    atomicAdd(&gq[col], q_);
    __syncthreads();
    if (t < 32) {
      atomicAdd(&sum1[vt * 32 + t], gs[t]);
      atomicAdd(&ss1[vt * 32 + t], gq[t]);
    }
  }
}

// ---------------- apply GN1 (affine inline) + SiLU -> h1 ----------------
__global__ void apply_gn1(const float* __restrict__ x,
                          const float* __restrict__ sum1, const float* __restrict__ ss1,
                          const float* __restrict__ gs, const float* __restrict__ gb,
                          bf16_t* __restrict__ h1) {
  size_t base = ((size_t)blockIdx.x * 256 + threadIdx.x) * 8;
  int vt = (int)(base / ((size_t)S_TOT * F_IN));
  int c0 = (int)(base & (F_IN - 1));
  const f32x4* xp = (const f32x4*)(x + base);
  f32x4 v0 = xp[0], v1 = xp[1];
  float N = (float)(S_TOT * 4);
  bf16x8 o;
#pragma unroll
  for (int gi = 0; gi < 2; ++gi) {
    int g = (c0 >> 2) + gi;
    float mean = sum1[vt * 32 + g] / N;
    float var = ss1[vt * 32 + g] / N - mean * mean;
    float r = rsqrtf(var + EPS);
    f32x4 v = gi ? v1 : v0;
#pragma unroll
    for (int j = 0; j < 4; ++j) {
      int c = g * 4 + j;
      float a = r * gs[c];
      float b = gb[c] - mean * a;
      o[gi * 4 + j] = (bf16_t)silu_f(v[j] * a + b);
    }
  }
  *(bf16x8*)(h1 + base) = o;
}

// ---------------- apply GN2 (affine inline) + SiLU in place ----------------
__global__ void apply_gn2(bf16_t* __restrict__ h,
                          const float* __restrict__ sum_c, const float* __restrict__ ss_c,
                          const float* __restrict__ gs, const float* __restrict__ gb) {
  size_t base = ((size_t)blockIdx.x * 256 + threadIdx.x) * 8;
  int vt = (int)(base / ((size_t)S_TOT * F_OUT));
  int c0 = (int)(base & (F_OUT - 1));
  int g = c0 >> 3;
  bf16x8 v = *(const bf16x8*)(h + base);
  float sg = 0.f, qg = 0.f;
#pragma unroll
  for (int j = 0; j < 8; ++j) {
    sg += sum_c[vt * 256 + g * 8 + j];
    qg += ss_c[vt * 256 + g * 8 + j];
  }
  float N = (float)(S_TOT * 8);
  float mean = sg / N;
  float var = qg / N - mean * mean;
  float r = rsqrtf(var + EPS);
  bf16x8 o;
#pragma unroll
  for (int j = 0; j < 8; ++j) {
    int c = g * 8 + j;
    float a = r * gs[c];
    float b = gb[c] - mean * a;
    o[j] = (bf16_t)silu_f((float)v[j] * a + b);
  }
  *(bf16x8*)(h + base) = o;
}

// ---------------- unified gather-conv GEMM v6 ----------------
// Block tile 96 rows x FULL 256 cols; 256 threads = 4 waves, wave tile 96x64.
// acc[6][4] (96 VGPR). A gathered once per row (full-N) into LDS ring-3 via
// global_load_lds, 64B rows, XOR seg swizzle. B: DIRECT global->reg via inline-asm
// dwordx4 loads, reg-double-buffered (b0/b1). Uniform 6 VMEM/wave/substage
// (dummy gll pads A staging) -> exact counted vmcnt across raw s_barrier.
template<int RE, int NSUB, bool XSK>
__global__ __launch_bounds__(256, 2) void conv_kernel(
    const bf16_t* __restrict__ hsrc, const bf16_t* __restrict__ Wp,
    const bf16_t* __restrict__ Wsp, const float* __restrict__ x,
    const int* __restrict__ adjc, const float* __restrict__ bias,
    const float* __restrict__ biask, bf16_t* __restrict__ outb,
    float* __restrict__ outf, float* __restrict__ sum_c, float* __restrict__ ss_c) {
  const int tid = threadIdx.x;
  const int wv = tid >> 6, l = tid & 63;
  const int lo = l & 15, hi = l >> 4;
  const int nw = wv;

  int swz = ((blockIdx.x & 7) << 6) + (blockIdx.x >> 3);   // bijective: 512 = 8*64
  int vt = swz >> 7;
  int sblk = swz & 127;
  int s0 = sblk * 96;

  __shared__ int adjs[864];
  __shared__ bf16_t ab[3][4096];   // per buf: 96 rows x 32 elems + 2x512 scratch

  for (int i = tid; i < 864; i += 256) adjs[i] = adjc[s0 * 9 + i];
  __syncthreads();

  const bf16_t* hb = hsrc + (size_t)vt * ((size_t)S_TOT * RE);
  constexpr int TPK = RE / 32;
  constexpr int NMAIN = XSK ? (NSUB - 4) : NSUB;

  // A-stage: exactly 2 gll16 per wave. j in {wv} u {4+wv real | dummy}.
  auto stageA = [&](int buf, int s) {
    int tap = s / TPK, chunk = s - tap * TPK;
    {
      int j = wv;
      int row = j * 16 + (l >> 2);
      int segs = (l & 3) ^ ((row >> 1) & 3);
      const bf16_t* g = hb + (size_t)adjs[row * 9 + tap] * RE + chunk * 32 + segs * 8;
      gll16(g, &ab[buf][j * 512]);
    }
    if (wv < 2) {
      int j = 4 + wv;
      int row = j * 16 + (l >> 2);
      int segs = (l & 3) ^ ((row >> 1) & 3);
      const bf16_t* g = hb + (size_t)adjs[row * 9 + tap] * RE + chunk * 32 + segs * 8;
      gll16(g, &ab[buf][j * 512]);
    } else {
      gll16(Wp + l * 8, &ab[buf][(4 + wv) * 512]);   // dummy: uniform vmcnt, scratch dest
    }
  };

  // B-stage: 4 asm global loads into regs (1 KB frag each), wave's 64-col strip.
  auto asmB = [&](i32x4* dst, const bf16_t* wsrc, int kcg) {
    const bf16_t* p = wsrc + (size_t)kcg * 8192 + nw * 2048 + l * 8;
    asm volatile(
        "global_load_dwordx4 %0, %4, off\n\t"
        "global_load_dwordx4 %1, %4, off offset:1024\n\t"
        "global_load_dwordx4 %2, %4, off offset:2048\n\t"
        "global_load_dwordx4 %3, %4, off offset:3072"
        : "=&v"(dst[0]), "=&v"(dst[1]), "=&v"(dst[2]), "=&v"(dst[3])
        : "v"(p));
  };

  // x-skip stage: f32 -> bf16 reg path into same swizzled A layout.
  auto stageX = [&](int buf, int sx) {
    if (tid < 192) {
      int row = tid >> 1, h = tid & 1;
      const float* xr = x + ((size_t)vt * S_TOT + s0 + row) * F_IN + sx * 32 + h * 16;
      f32x4 xv[4];
#pragma unroll
      for (int i = 0; i < 4; ++i) xv[i] = *(const f32x4*)(xr + i * 4);
#pragma unroll
      for (int i = 0; i < 2; ++i) {
        bf16x8 w;
#pragma unroll
        for (int jj = 0; jj < 4; ++jj) {
          w[jj] = (bf16_t)xv[2 * i][jj];
          w[4 + jj] = (bf16_t)xv[2 * i + 1][jj];
        }
        int seg = 2 * h + i;
        *(bf16x8*)(&ab[buf][row * 32 + ((seg ^ ((row >> 1) & 3)) << 3)]) = w;
      }
    }
  };

  f32x4 acc[6][4] = {};
  auto compute = [&](int buf, const i32x4* bv) {
    bf16x8 afr[6];
#pragma unroll
    for (int mi = 0; mi < 6; ++mi) {
      int rr = mi * 16 + lo;
      afr[mi] = *(const bf16x8*)(&ab[buf][rr * 32 + ((hi ^ ((rr >> 1) & 3)) << 3)]);
    }
    __builtin_amdgcn_s_setprio(1);
#pragma unroll
    for (int mi = 0; mi < 6; ++mi)
#pragma unroll
      for (int ni = 0; ni < 4; ++ni)
        acc[mi][ni] = __builtin_amdgcn_mfma_f32_16x16x32_bf16(
            afr[mi], __builtin_bit_cast(bf16x8, bv[ni]), acc[mi][ni], 0, 0, 0);
    __builtin_amdgcn_s_setprio(0);
  };

  i32x4 b0[4], b1[4];
  stageA(0, 0);
  stageA(1, 1);
  asmB(b0, Wp, 0);
  int bcur3 = 0, bstg3 = 2;

  for (int s = 0; s < NMAIN - 2; s += 2) {
    // even body: use b0, load b1
    asm volatile("s_waitcnt vmcnt(6)" ::: "memory");
    __builtin_amdgcn_s_barrier();
    __builtin_amdgcn_sched_barrier(0);
    stageA(bstg3, s + 2);
    asmB(b1, Wp, s + 1);
    asm volatile("s_waitcnt vmcnt(6)" ::: "memory");
    __builtin_amdgcn_sched_barrier(0);
    compute(bcur3, b0);
    bcur3 = (bcur3 == 2) ? 0 : bcur3 + 1;
    bstg3 = (bstg3 == 2) ? 0 : bstg3 + 1;
    // odd body: use b1, load b0
    asm volatile("s_waitcnt vmcnt(6)" ::: "memory");
    __builtin_amdgcn_s_barrier();
    __builtin_amdgcn_sched_barrier(0);
    stageA(bstg3, s + 3);
    asmB(b0, Wp, s + 2);
    asm volatile("s_waitcnt vmcnt(6)" ::: "memory");
    __builtin_amdgcn_sched_barrier(0);
    compute(bcur3, b1);
    bcur3 = (bcur3 == 2) ? 0 : bcur3 + 1;
    bstg3 = (bstg3 == 2) ? 0 : bstg3 + 1;
  }
  // body NMAIN-2 (even parity: use b0, load last B into b1)
  asm volatile("s_waitcnt vmcnt(6)" ::: "memory");
  __builtin_amdgcn_s_barrier();
  __builtin_amdgcn_sched_barrier(0);
  asmB(b1, Wp, NMAIN - 1);
  asm volatile("s_waitcnt vmcnt(4)" ::: "memory");
  __builtin_amdgcn_sched_barrier(0);
  compute(bcur3, b0);
  bcur3 = (bcur3 == 2) ? 0 : bcur3 + 1;
  // body NMAIN-1 (use b1)
  asm volatile("s_waitcnt vmcnt(4)" ::: "memory");
  __builtin_amdgcn_s_barrier();
  __builtin_amdgcn_sched_barrier(0);
  asm volatile("s_waitcnt vmcnt(0)" ::: "memory");
  __builtin_amdgcn_sched_barrier(0);
  compute(bcur3, b1);

  // ---- x-skip tail: 4 K32 substages from f32 x with W_skip ----
  if (XSK) {
#pragma unroll
    for (int sx = 0; sx < 4; ++sx) {
      int tb = sx & 1;
      __syncthreads();
      stageX(tb, sx);
      if (sx & 1) asmB(b1, Wsp, sx); else asmB(b0, Wsp, sx);
      asm volatile("s_waitcnt vmcnt(0)" ::: "memory");
      __syncthreads();
      __builtin_amdgcn_sched_barrier(0);
      compute(tb, (sx & 1) ? (const i32x4*)b1 : (const i32x4*)b0);
    }
  }

  if (!XSK) {
    bf16_t* ob = outb + ((size_t)vt * S_TOT + s0) * 256;
#pragma unroll
    for (int ni = 0; ni < 4; ++ni) {
      int o = nw * 64 + ni * 16 + lo;
      float bv = bias[o];
      float s_ = 0.f, q_ = 0.f;
#pragma unroll
      for (int mi = 0; mi < 6; ++mi)
#pragma unroll
        for (int r2 = 0; r2 < 4; ++r2) {
          int srow = mi * 16 + hi * 4 + r2;
          float v = acc[mi][ni][r2] + bv;
          ob[(size_t)srow * 256 + o] = (bf16_t)v;
          s_ += v; q_ += v * v;
        }
      s_ += __shfl_xor(s_, 16); s_ += __shfl_xor(s_, 32);
      q_ += __shfl_xor(q_, 16); q_ += __shfl_xor(q_, 32);
      if (hi == 0) {
        atomicAdd(&sum_c[vt * 256 + o], s_);
        atomicAdd(&ss_c[vt * 256 + o], q_);
      }
    }
  } else {
    float* of = outf + ((size_t)vt * S_TOT + s0) * 256;
#pragma unroll
    for (int ni = 0; ni < 4; ++ni) {
      int o = nw * 64 + ni * 16 + lo;
      float bv = bias[o] + biask[o];
#pragma unroll
      for (int mi = 0; mi < 6; ++mi)
#pragma unroll
        for (int r2 = 0; r2 < 4; ++r2) {
          int srow = mi * 16 + hi * 4 + r2;
          of[(size_t)srow * 256 + o] = acc[mi][ni][r2] + bv;
        }
    }
  }
}

extern "C" void kernel_launch(void* const* d_in, const int* in_sizes, int n_in,
                              void* d_out, int out_size, void* d_ws, size_t ws_size,
                              hipStream_t stream) {
  const float* x      = (const float*)d_in[0];
  const int*   adjc   = (const int*)d_in[1];
  const float* gn1_s  = (const float*)d_in[2];
  const float* gn1_b  = (const float*)d_in[3];
  const float* gn2_s  = (const float*)d_in[4];
  const float* gn2_b  = (const float*)d_in[5];
  const float* W_skip = (const float*)d_in[6];
  const float* b_skip = (const float*)d_in[7];
  const float* W1     = (const float*)d_in[8];
  const float* b1     = (const float*)d_in[9];
  const float* W2     = (const float*)d_in[10];
  const float* b2     = (const float*)d_in[11];
  float* out = (float*)d_out;

  float* sum1  = (float*)d_ws;           // 128
  float* ss1   = sum1 + 128;             // 128
  float* sum_c = ss1 + 128;              // 1024
  float* ss_c  = sum_c + 1024;           // 1024
  float* pad   = ss_c + 1024;            // 3072 (layout pad)
  bf16_t* W1p  = (bf16_t*)(pad + 3072);  // 294912
  bf16_t* W2p  = W1p + 294912;           // 589824
  bf16_t* Wsp  = W2p + 589824;           // 32768
  bf16_t* h1   = Wsp + 32768;            // 6291456
  bf16_t* out1 = h1 + 6291456;           // 12582912 (reused in place as h2)

  hipMemsetAsync(sum1, 0, (128 + 128 + 1024 + 1024) * sizeof(float), stream);
  prep_kernel<<<640, 256, 0, stream>>>(W1, W2, W_skip, W1p, W2p, Wsp, x, sum1, ss1);
  apply_gn1<<<3072, 256, 0, stream>>>(x, sum1, ss1, gn1_s, gn1_b, h1);
  conv_kernel<128, 36, false><<<512, 256, 0, stream>>>(
      h1, W1p, nullptr, nullptr, adjc, b1, nullptr, out1, nullptr, sum_c, ss_c);
  apply_gn2<<<6144, 256, 0, stream>>>(out1, sum_c, ss_c, gn2_s, gn2_b);
  conv_kernel<256, 76, true><<<512, 256, 0, stream>>>(
      out1, W2p, Wsp, x, adjc, b2, b_skip, nullptr, out, nullptr, nullptr);
}

// Round 7
// 144.317 us; speedup vs baseline: 1.4004x; 1.0547x over previous
//
#include <hip/hip_runtime.h>
#include <hip/hip_bf16.h>

typedef __bf16 bf16_t;
typedef __bf16 bf16x8 __attribute__((ext_vector_type(8)));
typedef float f32x4 __attribute__((ext_vector_type(4)));
typedef int i32x4 __attribute__((ext_vector_type(4)));

#define S_TOT 12288
#define F_IN 128
#define F_OUT 256
#define EPS 1e-5f

static __device__ __forceinline__ float silu_f(float v) {
  return v / (1.0f + __expf(-v));
}

static __device__ __forceinline__ void gll16(const bf16_t* g, bf16_t* l) {
  __builtin_amdgcn_global_load_lds(
      (const __attribute__((address_space(1))) void*)(const void*)g,
      (__attribute__((address_space(3))) void*)(void*)l, 16, 0, 0);
}

// ---------------- prep: pack weights (blocks 0..447) + GN1 stats (448..639) ----
// CHUNK-MAJOR pack: kcg = chunk*9 + tap (chunk = K32 slice, tap = neighbor k).
// Unit (kcg, cb): lane l holds B[f=32*chunk+8*(l>>4)+j of W_tap][o=16cb+(l&15)]
// at unit*1024B + l*16B. W1: 36 kcg; W2: 72 kcg; Wsk: 4 (chunk only).
__global__ void prep_kernel(const float* __restrict__ W1,
                            const float* __restrict__ W2,
                            const float* __restrict__ Wsk,
                            bf16_t* __restrict__ W1p,
                            bf16_t* __restrict__ W2p,
                            bf16_t* __restrict__ Wsp,
                            const float* __restrict__ x,
                            float* __restrict__ sum1, float* __restrict__ ss1) {
  __shared__ float gs[32], gq[32];
  if (blockIdx.x < 448) {
    int w = blockIdx.x * 4 + (threadIdx.x >> 6);
    int l = threadIdx.x & 63;
    int lo = l & 15, hi = l >> 4;
    const float* src;
    bf16_t* dst;
    int fbase, obase;
    if (w < 576) {
      int kcg = w >> 4, cb = w & 15;
      int tap = kcg % 9, chunk = kcg / 9;
      src = W1 + tap * 32768;
      dst = W1p + (size_t)w * 512;
      fbase = 32 * chunk + 8 * hi; obase = 16 * cb + lo;
    } else if (w < 1728) {
      int idx = w - 576;
      int kcg = idx >> 4, cb = idx & 15;
      int tap = kcg % 9, chunk = kcg / 9;
      src = W2 + tap * 65536;
      dst = W2p + (size_t)idx * 512;
      fbase = 32 * chunk + 8 * hi; obase = 16 * cb + lo;
    } else {
      int idx = w - 1728;
      int kc = idx >> 4, cb = idx & 15;
      src = Wsk;
      dst = Wsp + (size_t)idx * 512;
      fbase = 32 * kc + 8 * hi; obase = 16 * cb + lo;
    }
    bf16x8 v;
#pragma unroll
    for (int j = 0; j < 8; ++j)
      v[j] = (bf16_t)src[(fbase + j) * 256 + obase];
    *(bf16x8*)(dst + l * 8) = v;
  } else {
    int blk = blockIdx.x - 448;
    int vt = blk & 3;
    int s0 = (blk >> 2) * 256;
    int t = threadIdx.x;
    int col = t & 31, ro = t >> 5;
    float s_ = 0.f, q_ = 0.f;
    const f32x4* xp = (const f32x4*)(x + ((size_t)vt * S_TOT + s0) * F_IN);
#pragma unroll 4
    for (int it = 0; it < 32; ++it) {
      f32x4 v = xp[(size_t)(it * 8 + ro) * 32 + col];
      s_ += v[0] + v[1] + v[2] + v[3];
      q_ += v[0]*v[0] + v[1]*v[1] + v[2]*v[2] + v[3]*v[3];
    }
    if (t < 32) { gs[t] = 0.f; gq[t] = 0.f; }
    __syncthreads();
    atomicAdd(&gs[col], s_);
    atomicAdd(&gq[col], q_);
    __syncthreads();
    if (t < 32) {
      atomicAdd(&sum1[vt * 32 + t], gs[t]);
      atomicAdd(&ss1[vt * 32 + t], gq[t]);
    }
  }
}

// ---------------- apply GN1 (affine inline) + SiLU -> h1 ----------------
__global__ void apply_gn1(const float* __restrict__ x,
                          const float* __restrict__ sum1, const float* __restrict__ ss1,
                          const float* __restrict__ gs, const float* __restrict__ gb,
                          bf16_t* __restrict__ h1) {
  size_t base = ((size_t)blockIdx.x * 256 + threadIdx.x) * 8;
  int vt = (int)(base / ((size_t)S_TOT * F_IN));
  int c0 = (int)(base & (F_IN - 1));
  const f32x4* xp = (const f32x4*)(x + base);
  f32x4 v0 = xp[0], v1 = xp[1];
  float N = (float)(S_TOT * 4);
  bf16x8 o;
#pragma unroll
  for (int gi = 0; gi < 2; ++gi) {
    int g = (c0 >> 2) + gi;
    float mean = sum1[vt * 32 + g] / N;
    float var = ss1[vt * 32 + g] / N - mean * mean;
    float r = rsqrtf(var + EPS);
    f32x4 v = gi ? v1 : v0;
#pragma unroll
    for (int j = 0; j < 4; ++j) {
      int c = g * 4 + j;
      float a = r * gs[c];
      float b = gb[c] - mean * a;
      o[gi * 4 + j] = (bf16_t)silu_f(v[j] * a + b);
    }
  }
  *(bf16x8*)(h1 + base) = o;
}

// ---------------- apply GN2 (affine inline) + SiLU in place ----------------
__global__ void apply_gn2(bf16_t* __restrict__ h,
                          const float* __restrict__ sum_c, const float* __restrict__ ss_c,
                          const float* __restrict__ gs, const float* __restrict__ gb) {
  size_t base = ((size_t)blockIdx.x * 256 + threadIdx.x) * 8;
  int vt = (int)(base / ((size_t)S_TOT * F_OUT));
  int c0 = (int)(base & (F_OUT - 1));
  int g = c0 >> 3;
  bf16x8 v = *(const bf16x8*)(h + base);
  float sg = 0.f, qg = 0.f;
#pragma unroll
  for (int j = 0; j < 8; ++j) {
    sg += sum_c[vt * 256 + g * 8 + j];
    qg += ss_c[vt * 256 + g * 8 + j];
  }
  float N = (float)(S_TOT * 8);
  float mean = sg / N;
  float var = qg / N - mean * mean;
  float r = rsqrtf(var + EPS);
  bf16x8 o;
#pragma unroll
  for (int j = 0; j < 8; ++j) {
    int c = g * 8 + j;
    float a = r * gs[c];
    float b = gb[c] - mean * a;
    o[j] = (bf16_t)silu_f((float)v[j] * a + b);
  }
  *(bf16x8*)(h + base) = o;
}

// ---------------- unified gather-conv GEMM v7 ----------------
// Block 96 rows x FULL 256 cols; 4 waves, wave tile 96x64, acc[6][4].
// CHUNK-MAJOR substage order: s -> (chunk = s/9, tap = s%9); weights packed to
// match (B address linear in s). Per-XCD gather live-set ~1 MB -> L2-resident.
// Schedule/body: asmB(s+1); vmcnt(6); s_barrier; stageA(s+2); compute(s).
// Drain order leaves {A(s+1),B(s+1)} in flight: A gets 2 bodies of latency
// slack (~2200cy, covers HBM), B 1 body (L2-hot weights).
template<int RE, int NSUB, bool XSK>
__global__ __launch_bounds__(256, 2) void conv_kernel(
    const bf16_t* __restrict__ hsrc, const bf16_t* __restrict__ Wp,
    const bf16_t* __restrict__ Wsp, const float* __restrict__ x,
    const int* __restrict__ adjc, const float* __restrict__ bias,
    const float* __restrict__ biask, bf16_t* __restrict__ outb,
    float* __restrict__ outf, float* __restrict__ sum_c, float* __restrict__ ss_c) {
  const int tid = threadIdx.x;
  const int wv = tid >> 6, l = tid & 63;
  const int lo = l & 15, hi = l >> 4;
  const int nw = wv;

  int swz = ((blockIdx.x & 7) << 6) + (blockIdx.x >> 3);   // bijective: 512 = 8*64
  int vt = swz >> 7;
  int sblk = swz & 127;
  int s0 = sblk * 96;

  __shared__ int adjs[864];
  __shared__ bf16_t ab[3][4096];   // per buf: 96 rows x 32 elems + 2x512 scratch

  for (int i = tid; i < 864; i += 256) adjs[i] = adjc[s0 * 9 + i];
  __syncthreads();

  const bf16_t* hb = hsrc + (size_t)vt * ((size_t)S_TOT * RE);
  constexpr int NMAIN = XSK ? (NSUB - 4) : NSUB;

  // A-stage for substage (tap, chunk): exactly 2 gll16 per wave (1 dummy pad).
  auto stageA = [&](int buf, int tap, int chunk) {
    {
      int j = wv;
      int row = j * 16 + (l >> 2);
      int segs = (l & 3) ^ ((row >> 1) & 3);
      const bf16_t* g = hb + (size_t)adjs[row * 9 + tap] * RE + chunk * 32 + segs * 8;
      gll16(g, &ab[buf][j * 512]);
    }
    if (wv < 2) {
      int j = 4 + wv;
      int row = j * 16 + (l >> 2);
      int segs = (l & 3) ^ ((row >> 1) & 3);
      const bf16_t* g = hb + (size_t)adjs[row * 9 + tap] * RE + chunk * 32 + segs * 8;
      gll16(g, &ab[buf][j * 512]);
    } else {
      gll16(Wp + l * 8, &ab[buf][(4 + wv) * 512]);   // dummy: uniform vmcnt count
    }
  };

  // B-stage: 4 asm global loads into regs, wave's 64-col strip of kcg = s.
  auto asmB = [&](i32x4* dst, const bf16_t* wsrc, int kcg) {
    const bf16_t* p = wsrc + (size_t)kcg * 8192 + nw * 2048 + l * 8;
    asm volatile(
        "global_load_dwordx4 %0, %4, off\n\t"
        "global_load_dwordx4 %1, %4, off offset:1024\n\t"
        "global_load_dwordx4 %2, %4, off offset:2048\n\t"
        "global_load_dwordx4 %3, %4, off offset:3072"
        : "=&v"(dst[0]), "=&v"(dst[1]), "=&v"(dst[2]), "=&v"(dst[3])
        : "v"(p));
  };

  // x-skip stage: f32 -> bf16 reg path into same swizzled A layout.
  auto stageX = [&](int buf, int sx) {
    if (tid < 192) {
      int row = tid >> 1, h = tid & 1;
      const float* xr = x + ((size_t)vt * S_TOT + s0 + row) * F_IN + sx * 32 + h * 16;
      f32x4 xv[4];
#pragma unroll
      for (int i = 0; i < 4; ++i) xv[i] = *(const f32x4*)(xr + i * 4);
#pragma unroll
      for (int i = 0; i < 2; ++i) {
        bf16x8 w;
#pragma unroll
        for (int jj = 0; jj < 4; ++jj) {
          w[jj] = (bf16_t)xv[2 * i][jj];
          w[4 + jj] = (bf16_t)xv[2 * i + 1][jj];
        }
        int seg = 2 * h + i;
        *(bf16x8*)(&ab[buf][row * 32 + ((seg ^ ((row >> 1) & 3)) << 3)]) = w;
      }
    }
  };

  f32x4 acc[6][4] = {};
  auto compute = [&](int buf, const i32x4* bv) {
    bf16x8 afr[6];
#pragma unroll
    for (int mi = 0; mi < 6; ++mi) {
      int rr = mi * 16 + lo;
      afr[mi] = *(const bf16x8*)(&ab[buf][rr * 32 + ((hi ^ ((rr >> 1) & 3)) << 3)]);
    }
    __builtin_amdgcn_s_setprio(1);
#pragma unroll
    for (int mi = 0; mi < 6; ++mi)
#pragma unroll
      for (int ni = 0; ni < 4; ++ni)
        acc[mi][ni] = __builtin_amdgcn_mfma_f32_16x16x32_bf16(
            afr[mi], __builtin_bit_cast(bf16x8, bv[ni]), acc[mi][ni], 0, 0, 0);
    __builtin_amdgcn_s_setprio(0);
  };

  i32x4 b0[4], b1[4];
  // Prologue. Issue order A0, B0, A1 -> steady invariant at each body top:
  // in-flight = A(s)[2], B(s)[4], A(s+1)[2].
  stageA(0, 0, 0);
  asmB(b0, Wp, 0);
  stageA(1, 1, 0);
  int bcur3 = 0, bstg3 = 2;
  // (tap, chunk) decomposition of s+2, tracked as uniform counters.
  int t2 = 2, c2 = 0;

  for (int s = 0; s < NMAIN - 2; s += 2) {
    // even body: use b0, load b1
    asmB(b1, Wp, s + 1);
    asm volatile("s_waitcnt vmcnt(6)" ::: "memory");  // A(s),B(s) landed
    __builtin_amdgcn_s_barrier();
    __builtin_amdgcn_sched_barrier(0);
    stageA(bstg3, t2, c2);
    if (++t2 == 9) { t2 = 0; ++c2; }
    compute(bcur3, b0);
    bcur3 = (bcur3 == 2) ? 0 : bcur3 + 1;
    bstg3 = (bstg3 == 2) ? 0 : bstg3 + 1;
    // odd body: use b1, load b0
    asmB(b0, Wp, s + 2);
    asm volatile("s_waitcnt vmcnt(6)" ::: "memory");
    __builtin_amdgcn_s_barrier();
    __builtin_amdgcn_sched_barrier(0);
    stageA(bstg3, t2, c2);
    if (++t2 == 9) { t2 = 0; ++c2; }
    compute(bcur3, b1);
    bcur3 = (bcur3 == 2) ? 0 : bcur3 + 1;
    bstg3 = (bstg3 == 2) ? 0 : bstg3 + 1;
  }
  // body NMAIN-2 (even parity: use b0, load last B into b1; no more stageA)
  asmB(b1, Wp, NMAIN - 1);
  asm volatile("s_waitcnt vmcnt(6)" ::: "memory");
  __builtin_amdgcn_s_barrier();
  __builtin_amdgcn_sched_barrier(0);
  compute(bcur3, b0);
  bcur3 = (bcur3 == 2) ? 0 : bcur3 + 1;
  // body NMAIN-1 (use b1)
  asm volatile("s_waitcnt vmcnt(0)" ::: "memory");
  __builtin_amdgcn_s_barrier();
  __builtin_amdgcn_sched_barrier(0);
  compute(bcur3, b1);

  // ---- x-skip tail: 4 K32 substages from f32 x with W_skip ----
  if (XSK) {
#pragma unroll
    for (int sx = 0; sx < 4; ++sx) {
      int tb = sx & 1;
      __syncthreads();
      stageX(tb, sx);
      if (sx & 1) asmB(b1, Wsp, sx); else asmB(b0, Wsp, sx);
      asm volatile("s_waitcnt vmcnt(0)" ::: "memory");
      __syncthreads();
      __builtin_amdgcn_sched_barrier(0);
      compute(tb, (sx & 1) ? (const i32x4*)b1 : (const i32x4*)b0);
    }
  }

  if (!XSK) {
    bf16_t* ob = outb + ((size_t)vt * S_TOT + s0) * 256;
#pragma unroll
    for (int ni = 0; ni < 4; ++ni) {
      int o = nw * 64 + ni * 16 + lo;
      float bv = bias[o];
      float s_ = 0.f, q_ = 0.f;
#pragma unroll
      for (int mi = 0; mi < 6; ++mi)
#pragma unroll
        for (int r2 = 0; r2 < 4; ++r2) {
          int srow = mi * 16 + hi * 4 + r2;
          float v = acc[mi][ni][r2] + bv;
          ob[(size_t)srow * 256 + o] = (bf16_t)v;
          s_ += v; q_ += v * v;
        }
      s_ += __shfl_xor(s_, 16); s_ += __shfl_xor(s_, 32);
      q_ += __shfl_xor(q_, 16); q_ += __shfl_xor(q_, 32);
      if (hi == 0) {
        atomicAdd(&sum_c[vt * 256 + o], s_);
        atomicAdd(&ss_c[vt * 256 + o], q_);
      }
    }
  } else {
    float* of = outf + ((size_t)vt * S_TOT + s0) * 256;
#pragma unroll
    for (int ni = 0; ni < 4; ++ni) {
      int o = nw * 64 + ni * 16 + lo;
      float bv = bias[o] + biask[o];
#pragma unroll
      for (int mi = 0; mi < 6; ++mi)
#pragma unroll
        for (int r2 = 0; r2 < 4; ++r2) {
          int srow = mi * 16 + hi * 4 + r2;
          of[(size_t)srow * 256 + o] = acc[mi][ni][r2] + bv;
        }
    }
  }
}

extern "C" void kernel_launch(void* const* d_in, const int* in_sizes, int n_in,
                              void* d_out, int out_size, void* d_ws, size_t ws_size,
                              hipStream_t stream) {
  const float* x      = (const float*)d_in[0];
  const int*   adjc   = (const int*)d_in[1];
  const float* gn1_s  = (const float*)d_in[2];
  const float* gn1_b  = (const float*)d_in[3];
  const float* gn2_s  = (const float*)d_in[4];
  const float* gn2_b  = (const float*)d_in[5];
  const float* W_skip = (const float*)d_in[6];
  const float* b_skip = (const float*)d_in[7];
  const float* W1     = (const float*)d_in[8];
  const float* b1     = (const float*)d_in[9];
  const float* W2     = (const float*)d_in[10];
  const float* b2     = (const float*)d_in[11];
  float* out = (float*)d_out;

  float* sum1  = (float*)d_ws;           // 128
  float* ss1   = sum1 + 128;             // 128
  float* sum_c = ss1 + 128;              // 1024
  float* ss_c  = sum_c + 1024;           // 1024
  float* pad   = ss_c + 1024;            // 3072 (layout pad)
  bf16_t* W1p  = (bf16_t*)(pad + 3072);  // 294912
  bf16_t* W2p  = W1p + 294912;           // 589824
  bf16_t* Wsp  = W2p + 589824;           // 32768
  bf16_t* h1   = Wsp + 32768;            // 6291456
  bf16_t* out1 = h1 + 6291456;           // 12582912 (reused in place as h2)

  hipMemsetAsync(sum1, 0, (128 + 128 + 1024 + 1024) * sizeof(float), stream);
  prep_kernel<<<640, 256, 0, stream>>>(W1, W2, W_skip, W1p, W2p, Wsp, x, sum1, ss1);
  apply_gn1<<<3072, 256, 0, stream>>>(x, sum1, ss1, gn1_s, gn1_b, h1);
  conv_kernel<128, 36, false><<<512, 256, 0, stream>>>(
      h1, W1p, nullptr, nullptr, adjc, b1, nullptr, out1, nullptr, sum_c, ss_c);
  apply_gn2<<<6144, 256, 0, stream>>>(out1, sum_c, ss_c, gn2_s, gn2_b);
  conv_kernel<256, 76, true><<<512, 256, 0, stream>>>(
      out1, W2p, Wsp, x, adjc, b2, b_skip, nullptr, out, nullptr, nullptr);
}

// Round 8
// 140.608 us; speedup vs baseline: 1.4373x; 1.0264x over previous
//
#include <hip/hip_runtime.h>
#include <hip/hip_bf16.h>

typedef __bf16 bf16_t;
typedef __bf16 bf16x8 __attribute__((ext_vector_type(8)));
typedef float f32x4 __attribute__((ext_vector_type(4)));
typedef int i32x4 __attribute__((ext_vector_type(4)));

#define S_TOT 12288
#define F_IN 128
#define F_OUT 256
#define EPS 1e-5f

static __device__ __forceinline__ float silu_f(float v) {
  return v / (1.0f + __expf(-v));
}

static __device__ __forceinline__ void gll16(const bf16_t* g, bf16_t* l) {
  __builtin_amdgcn_global_load_lds(
      (const __attribute__((address_space(1))) void*)(const void*)g,
      (__attribute__((address_space(3))) void*)(void*)l, 16, 0, 0);
}

// ---------------- prep: pack weights (blocks 0..447) + GN1 stats (448..639) ----
// CHUNK-MAJOR pack: kcg = chunk*9 + tap (chunk = K32 slice, tap = neighbor k).
// Unit (kcg, cb): lane l holds B[f=32*chunk+8*(l>>4)+j of W_tap][o=16cb+(l&15)]
// at unit*1024B + l*16B. W1: 36 kcg; W2: 72 kcg; Wsk: 4 (chunk only).
__global__ void prep_kernel(const float* __restrict__ W1,
                            const float* __restrict__ W2,
                            const float* __restrict__ Wsk,
                            bf16_t* __restrict__ W1p,
                            bf16_t* __restrict__ W2p,
                            bf16_t* __restrict__ Wsp,
                            const float* __restrict__ x,
                            float* __restrict__ sum1, float* __restrict__ ss1) {
  __shared__ float gs[32], gq[32];
  if (blockIdx.x < 448) {
    int w = blockIdx.x * 4 + (threadIdx.x >> 6);
    int l = threadIdx.x & 63;
    int lo = l & 15, hi = l >> 4;
    const float* src;
    bf16_t* dst;
    int fbase, obase;
    if (w < 576) {
      int kcg = w >> 4, cb = w & 15;
      int tap = kcg % 9, chunk = kcg / 9;
      src = W1 + tap * 32768;
      dst = W1p + (size_t)w * 512;
      fbase = 32 * chunk + 8 * hi; obase = 16 * cb + lo;
    } else if (w < 1728) {
      int idx = w - 576;
      int kcg = idx >> 4, cb = idx & 15;
      int tap = kcg % 9, chunk = kcg / 9;
      src = W2 + tap * 65536;
      dst = W2p + (size_t)idx * 512;
      fbase = 32 * chunk + 8 * hi; obase = 16 * cb + lo;
    } else {
      int idx = w - 1728;
      int kc = idx >> 4, cb = idx & 15;
      src = Wsk;
      dst = Wsp + (size_t)idx * 512;
      fbase = 32 * kc + 8 * hi; obase = 16 * cb + lo;
    }
    bf16x8 v;
#pragma unroll
    for (int j = 0; j < 8; ++j)
      v[j] = (bf16_t)src[(fbase + j) * 256 + obase];
    *(bf16x8*)(dst + l * 8) = v;
  } else {
    int blk = blockIdx.x - 448;
    int vt = blk & 3;
    int s0 = (blk >> 2) * 256;
    int t = threadIdx.x;
    int col = t & 31, ro = t >> 5;
    float s_ = 0.f, q_ = 0.f;
    const f32x4* xp = (const f32x4*)(x + ((size_t)vt * S_TOT + s0) * F_IN);
#pragma unroll 4
    for (int it = 0; it < 32; ++it) {
      f32x4 v = xp[(size_t)(it * 8 + ro) * 32 + col];
      s_ += v[0] + v[1] + v[2] + v[3];
      q_ += v[0]*v[0] + v[1]*v[1] + v[2]*v[2] + v[3]*v[3];
    }
    if (t < 32) { gs[t] = 0.f; gq[t] = 0.f; }
    __syncthreads();
    atomicAdd(&gs[col], s_);
    atomicAdd(&gq[col], q_);
    __syncthreads();
    if (t < 32) {
      atomicAdd(&sum1[vt * 32 + t], gs[t]);
      atomicAdd(&ss1[vt * 32 + t], gq[t]);
    }
  }
}

// ---------------- apply GN1 (affine inline) + SiLU -> h1 ----------------
__global__ void apply_gn1(const float* __restrict__ x,
                          const float* __restrict__ sum1, const float* __restrict__ ss1,
                          const float* __restrict__ gs, const float* __restrict__ gb,
                          bf16_t* __restrict__ h1) {
  size_t base = ((size_t)blockIdx.x * 256 + threadIdx.x) * 8;
  int vt = (int)(base / ((size_t)S_TOT * F_IN));
  int c0 = (int)(base & (F_IN - 1));
  const f32x4* xp = (const f32x4*)(x + base);
  f32x4 v0 = xp[0], v1 = xp[1];
  float N = (float)(S_TOT * 4);
  bf16x8 o;
#pragma unroll
  for (int gi = 0; gi < 2; ++gi) {
    int g = (c0 >> 2) + gi;
    float mean = sum1[vt * 32 + g] / N;
    float var = ss1[vt * 32 + g] / N - mean * mean;
    float r = rsqrtf(var + EPS);
    f32x4 v = gi ? v1 : v0;
#pragma unroll
    for (int j = 0; j < 4; ++j) {
      int c = g * 4 + j;
      float a = r * gs[c];
      float b = gb[c] - mean * a;
      o[gi * 4 + j] = (bf16_t)silu_f(v[j] * a + b);
    }
  }
  *(bf16x8*)(h1 + base) = o;
}

// ---------------- apply GN2 (affine inline) + SiLU in place ----------------
__global__ void apply_gn2(bf16_t* __restrict__ h,
                          const float* __restrict__ sum_c, const float* __restrict__ ss_c,
                          const float* __restrict__ gs, const float* __restrict__ gb) {
  size_t base = ((size_t)blockIdx.x * 256 + threadIdx.x) * 8;
  int vt = (int)(base / ((size_t)S_TOT * F_OUT));
  int c0 = (int)(base & (F_OUT - 1));
  int g = c0 >> 3;
  bf16x8 v = *(const bf16x8*)(h + base);
  float sg = 0.f, qg = 0.f;
#pragma unroll
  for (int j = 0; j < 8; ++j) {
    sg += sum_c[vt * 256 + g * 8 + j];
    qg += ss_c[vt * 256 + g * 8 + j];
  }
  float N = (float)(S_TOT * 8);
  float mean = sg / N;
  float var = qg / N - mean * mean;
  float r = rsqrtf(var + EPS);
  bf16x8 o;
#pragma unroll
  for (int j = 0; j < 8; ++j) {
    int c = g * 8 + j;
    float a = r * gs[c];
    float b = gb[c] - mean * a;
    o[j] = (bf16_t)silu_f((float)v[j] * a + b);
  }
  *(bf16x8*)(h + base) = o;
}

// ---------------- unified gather-conv GEMM v8 ----------------
// Block 64 rows x FULL 256 cols; 4 waves, wave tile 64x64, acc[4][4].
// Grid 768 = EXACTLY 3 blocks/CU (LDS 14.6KB) -> 3 waves/SIMD from independent
// blocks whose phases drift: MFMA of one block overlaps LDS/L1/waits of others.
// CHUNK-MAJOR substage order (s -> tap=s%9, chunk=s/9), weights packed to match.
// A: 1 gll16/wave (64 rows x 64B, XOR-swizzled source). B: 4 asm dwordx4 -> regs,
// double-buffered. Uniform 5 VMEM/wave/substage; steady wait vmcnt(5):
// A gets 2 bodies of flight, B 1 body (L2-hot).
template<int RE, int NSUB, bool XSK>
__global__ __launch_bounds__(256, 3) void conv_kernel(
    const bf16_t* __restrict__ hsrc, const bf16_t* __restrict__ Wp,
    const bf16_t* __restrict__ Wsp, const float* __restrict__ x,
    const int* __restrict__ adjc, const float* __restrict__ bias,
    const float* __restrict__ biask, bf16_t* __restrict__ outb,
    float* __restrict__ outf, float* __restrict__ sum_c, float* __restrict__ ss_c) {
  const int tid = threadIdx.x;
  const int wv = tid >> 6, l = tid & 63;
  const int lo = l & 15, hi = l >> 4;
  const int nw = wv;

  int swz = ((blockIdx.x & 7) * 96) + (blockIdx.x >> 3);   // bijective: 768 = 8*96
  int vt = swz / 192;
  int rem = swz - vt * 192;
  int s0 = rem * 64;

  __shared__ int adjs[576];
  __shared__ bf16_t ab[3][2048];   // per buf: 64 rows x 32 elems (64B rows)

  for (int i = tid; i < 576; i += 256) adjs[i] = adjc[s0 * 9 + i];
  __syncthreads();

  const bf16_t* hb = hsrc + (size_t)vt * ((size_t)S_TOT * RE);
  constexpr int NMAIN = XSK ? (NSUB - 4) : NSUB;

  // A-stage for substage (tap, chunk): exactly 1 gll16 per wave.
  auto stageA = [&](int buf, int tap, int chunk) {
    int row = wv * 16 + (l >> 2);
    int segs = (l & 3) ^ ((row >> 1) & 3);
    const bf16_t* g = hb + (size_t)adjs[row * 9 + tap] * RE + chunk * 32 + segs * 8;
    gll16(g, &ab[buf][wv * 512]);
  };

  // B-stage: 4 asm global loads into regs, wave's 64-col strip of kcg = s.
  auto asmB = [&](i32x4* dst, const bf16_t* wsrc, int kcg) {
    const bf16_t* p = wsrc + (size_t)kcg * 8192 + nw * 2048 + l * 8;
    asm volatile(
        "global_load_dwordx4 %0, %4, off\n\t"
        "global_load_dwordx4 %1, %4, off offset:1024\n\t"
        "global_load_dwordx4 %2, %4, off offset:2048\n\t"
        "global_load_dwordx4 %3, %4, off offset:3072"
        : "=&v"(dst[0]), "=&v"(dst[1]), "=&v"(dst[2]), "=&v"(dst[3])
        : "v"(p));
  };

  // x-skip stage: f32 -> bf16 reg path into same swizzled A layout.
  auto stageX = [&](int buf, int sx) {
    int row = tid >> 2, q = tid & 3;
    const float* xr = x + ((size_t)vt * S_TOT + s0 + row) * F_IN + sx * 32 + q * 8;
    f32x4 xv0 = *(const f32x4*)(xr);
    f32x4 xv1 = *(const f32x4*)(xr + 4);
    bf16x8 w;
#pragma unroll
    for (int jj = 0; jj < 4; ++jj) {
      w[jj] = (bf16_t)xv0[jj];
      w[4 + jj] = (bf16_t)xv1[jj];
    }
    *(bf16x8*)(&ab[buf][row * 32 + ((q ^ ((row >> 1) & 3)) << 3)]) = w;
  };

  f32x4 acc[4][4] = {};
  auto compute = [&](int buf, const i32x4* bv) {
    bf16x8 afr[4];
#pragma unroll
    for (int mi = 0; mi < 4; ++mi) {
      int rr = mi * 16 + lo;
      afr[mi] = *(const bf16x8*)(&ab[buf][rr * 32 + ((hi ^ ((rr >> 1) & 3)) << 3)]);
    }
    __builtin_amdgcn_s_setprio(1);
#pragma unroll
    for (int mi = 0; mi < 4; ++mi)
#pragma unroll
      for (int ni = 0; ni < 4; ++ni)
        acc[mi][ni] = __builtin_amdgcn_mfma_f32_16x16x32_bf16(
            afr[mi], __builtin_bit_cast(bf16x8, bv[ni]), acc[mi][ni], 0, 0, 0);
    __builtin_amdgcn_s_setprio(0);
  };

  i32x4 b0[4], b1[4];
  // Prologue: in-flight at body top = A(s)[1], B(s)[4], A(s+1)[1].
  stageA(0, 0, 0);
  asmB(b0, Wp, 0);
  stageA(1, 1, 0);
  int bcur3 = 0, bstg3 = 2;
  int t2 = 2, c2 = 0;   // (tap, chunk) of substage s+2

  for (int s = 0; s < NMAIN - 2; s += 2) {
    // even body: use b0, load b1
    asmB(b1, Wp, s + 1);
    asm volatile("s_waitcnt vmcnt(5)" ::: "memory");  // A(s),B(s) landed
    __builtin_amdgcn_s_barrier();
    __builtin_amdgcn_sched_barrier(0);
    stageA(bstg3, t2, c2);
    if (++t2 == 9) { t2 = 0; ++c2; }
    compute(bcur3, b0);
    bcur3 = (bcur3 == 2) ? 0 : bcur3 + 1;
    bstg3 = (bstg3 == 2) ? 0 : bstg3 + 1;
    // odd body: use b1, load b0
    asmB(b0, Wp, s + 2);
    asm volatile("s_waitcnt vmcnt(5)" ::: "memory");
    __builtin_amdgcn_s_barrier();
    __builtin_amdgcn_sched_barrier(0);
    stageA(bstg3, t2, c2);
    if (++t2 == 9) { t2 = 0; ++c2; }
    compute(bcur3, b1);
    bcur3 = (bcur3 == 2) ? 0 : bcur3 + 1;
    bstg3 = (bstg3 == 2) ? 0 : bstg3 + 1;
  }
  // body NMAIN-2 (even parity: use b0, load last B into b1; no more stageA)
  asmB(b1, Wp, NMAIN - 1);
  asm volatile("s_waitcnt vmcnt(5)" ::: "memory");
  __builtin_amdgcn_s_barrier();
  __builtin_amdgcn_sched_barrier(0);
  compute(bcur3, b0);
  bcur3 = (bcur3 == 2) ? 0 : bcur3 + 1;
  // body NMAIN-1 (use b1)
  asm volatile("s_waitcnt vmcnt(0)" ::: "memory");
  __builtin_amdgcn_s_barrier();
  __builtin_amdgcn_sched_barrier(0);
  compute(bcur3, b1);

  // ---- x-skip tail: 4 K32 substages from f32 x with W_skip ----
  if (XSK) {
#pragma unroll
    for (int sx = 0; sx < 4; ++sx) {
      int tb = sx & 1;
      __syncthreads();
      stageX(tb, sx);
      if (sx & 1) asmB(b1, Wsp, sx); else asmB(b0, Wsp, sx);
      asm volatile("s_waitcnt vmcnt(0)" ::: "memory");
      __syncthreads();
      __builtin_amdgcn_sched_barrier(0);
      compute(tb, (sx & 1) ? (const i32x4*)b1 : (const i32x4*)b0);
    }
  }

  if (!XSK) {
    bf16_t* ob = outb + ((size_t)vt * S_TOT + s0) * 256;
#pragma unroll
    for (int ni = 0; ni < 4; ++ni) {
      int o = nw * 64 + ni * 16 + lo;
      float bv = bias[o];
      float s_ = 0.f, q_ = 0.f;
#pragma unroll
      for (int mi = 0; mi < 4; ++mi)
#pragma unroll
        for (int r2 = 0; r2 < 4; ++r2) {
          int srow = mi * 16 + hi * 4 + r2;
          float v = acc[mi][ni][r2] + bv;
          ob[(size_t)srow * 256 + o] = (bf16_t)v;
          s_ += v; q_ += v * v;
        }
      s_ += __shfl_xor(s_, 16); s_ += __shfl_xor(s_, 32);
      q_ += __shfl_xor(q_, 16); q_ += __shfl_xor(q_, 32);
      if (hi == 0) {
        atomicAdd(&sum_c[vt * 256 + o], s_);
        atomicAdd(&ss_c[vt * 256 + o], q_);
      }
    }
  } else {
    float* of = outf + ((size_t)vt * S_TOT + s0) * 256;
#pragma unroll
    for (int ni = 0; ni < 4; ++ni) {
      int o = nw * 64 + ni * 16 + lo;
      float bv = bias[o] + biask[o];
#pragma unroll
      for (int mi = 0; mi < 4; ++mi)
#pragma unroll
        for (int r2 = 0; r2 < 4; ++r2) {
          int srow = mi * 16 + hi * 4 + r2;
          of[(size_t)srow * 256 + o] = acc[mi][ni][r2] + bv;
        }
    }
  }
}

extern "C" void kernel_launch(void* const* d_in, const int* in_sizes, int n_in,
                              void* d_out, int out_size, void* d_ws, size_t ws_size,
                              hipStream_t stream) {
  const float* x      = (const float*)d_in[0];
  const int*   adjc   = (const int*)d_in[1];
  const float* gn1_s  = (const float*)d_in[2];
  const float* gn1_b  = (const float*)d_in[3];
  const float* gn2_s  = (const float*)d_in[4];
  const float* gn2_b  = (const float*)d_in[5];
  const float* W_skip = (const float*)d_in[6];
  const float* b_skip = (const float*)d_in[7];
  const float* W1     = (const float*)d_in[8];
  const float* b1     = (const float*)d_in[9];
  const float* W2     = (const float*)d_in[10];
  const float* b2     = (const float*)d_in[11];
  float* out = (float*)d_out;

  float* sum1  = (float*)d_ws;           // 128
  float* ss1   = sum1 + 128;             // 128
  float* sum_c = ss1 + 128;              // 1024
  float* ss_c  = sum_c + 1024;           // 1024
  float* pad   = ss_c + 1024;            // 3072 (layout pad)
  bf16_t* W1p  = (bf16_t*)(pad + 3072);  // 294912
  bf16_t* W2p  = W1p + 294912;           // 589824
  bf16_t* Wsp  = W2p + 589824;           // 32768
  bf16_t* h1   = Wsp + 32768;            // 6291456
  bf16_t* out1 = h1 + 6291456;           // 12582912 (reused in place as h2)

  hipMemsetAsync(sum1, 0, (128 + 128 + 1024 + 1024) * sizeof(float), stream);
  prep_kernel<<<640, 256, 0, stream>>>(W1, W2, W_skip, W1p, W2p, Wsp, x, sum1, ss1);
  apply_gn1<<<3072, 256, 0, stream>>>(x, sum1, ss1, gn1_s, gn1_b, h1);
  conv_kernel<128, 36, false><<<768, 256, 0, stream>>>(
      h1, W1p, nullptr, nullptr, adjc, b1, nullptr, out1, nullptr, sum_c, ss_c);
  apply_gn2<<<6144, 256, 0, stream>>>(out1, sum_c, ss_c, gn2_s, gn2_b);
  conv_kernel<256, 76, true><<<768, 256, 0, stream>>>(
      out1, W2p, Wsp, x, adjc, b2, b_skip, nullptr, out, nullptr, nullptr);
}